// Round 2
// baseline (1410.004 us; speedup 1.0000x reference)
//
#include <hip/hip_runtime.h>
#include <hip/hip_bf16.h>
#include <cmath>

// Problem constants (B=8, H=W=112, C=192, heads=8, hd=24, ps=7, hid=768)
#define C_DIM 192
#define HID 768

typedef __attribute__((ext_vector_type(8))) __bf16 bf16x8;
typedef __attribute__((ext_vector_type(4))) float f32x4;

__device__ __forceinline__ void gload_lds16(const void* g, void* l) {
  __builtin_amdgcn_global_load_lds(
      (__attribute__((address_space(1))) void*)(const_cast<void*>(g)),
      (__attribute__((address_space(3))) void*)(l), 16, 0, 0);
}

// ---------------- prep: weights fp32 -> bf16 (+ fold q scale) ----------------
__global__ __launch_bounds__(256) void prep_kernel(
    const float* __restrict__ q_w, const float* __restrict__ q_b,
    const float* __restrict__ kv_w, const float* __restrict__ kv_b,
    const float* __restrict__ proj_w, const float* __restrict__ fc1_w,
    const float* __restrict__ fc2_w,
    __hip_bfloat16* __restrict__ wcat, float* __restrict__ bcat,
    __hip_bfloat16* __restrict__ projw, __hip_bfloat16* __restrict__ fc1w,
    __hip_bfloat16* __restrict__ fc2w)
{
  int idx = blockIdx.x * 256 + threadIdx.x;
  const float scale = 0.20412414523193154f;  // 24^-0.5
  if (idx < 110592) {  // 576 x 192 concat [q_w*scale ; kv_w]
    float v = (idx < 36864) ? q_w[idx] * scale : kv_w[idx - 36864];
    wcat[idx] = __float2bfloat16(v);
  }
  if (idx < 576) bcat[idx] = (idx < 192) ? q_b[idx] * scale : kv_b[idx - 192];
  if (idx < 36864) projw[idx] = __float2bfloat16(proj_w[idx]);
  if (idx < 147456) {
    fc1w[idx] = __float2bfloat16(fc1_w[idx]);
    fc2w[idx] = __float2bfloat16(fc2_w[idx]);
  }
}

// -------- LayerNorm fp32 -> bf16, one wave per token (192 = 64*3) -----------
__global__ __launch_bounds__(256) void ln_kernel(
    const float* __restrict__ x, const float* __restrict__ g,
    const float* __restrict__ b, __hip_bfloat16* __restrict__ out)
{
  int t = blockIdx.x * 4 + (threadIdx.x >> 6);
  int lane = threadIdx.x & 63;
  const float* xr = x + (size_t)t * C_DIM;
  float v0 = xr[lane], v1 = xr[lane + 64], v2 = xr[lane + 128];
  float s = v0 + v1 + v2;
  float sq = v0 * v0 + v1 * v1 + v2 * v2;
  #pragma unroll
  for (int off = 32; off > 0; off >>= 1) {
    s += __shfl_xor(s, off, 64);
    sq += __shfl_xor(sq, off, 64);
  }
  float mean = s * (1.0f / 192.0f);
  float var = sq * (1.0f / 192.0f) - mean * mean;
  float rstd = rsqrtf(var + 1e-5f);
  size_t o = (size_t)t * C_DIM;
  out[o + lane]       = __float2bfloat16((v0 - mean) * rstd * g[lane] + b[lane]);
  out[o + lane + 64]  = __float2bfloat16((v1 - mean) * rstd * g[lane + 64] + b[lane + 64]);
  out[o + lane + 128] = __float2bfloat16((v2 - mean) * rstd * g[lane + 128] + b[lane + 128]);
}

// -------- MFMA bf16 GEMM: out[M,N] = X[M,K](lda) @ W[N,K]^T + bias (+ add) --
// Block tile 128x64, 256 threads (4 waves, each 32x64 = 2x4 mfma tiles).
// EPI 0: bf16 store (acc + bias).  EPI 1: fp32 store (acc + bias + addin).
template <int EPI>
__global__ __launch_bounds__(256) void gemm_kernel(
    const ushort* __restrict__ X, int lda, const ushort* __restrict__ W,
    const float* __restrict__ bias, const float* __restrict__ addin,
    void* __restrict__ outp, int N, int K)
{
  __shared__ __align__(16) ushort Al[128 * 32];
  __shared__ __align__(16) ushort Bl[64 * 32];
  const int tid = threadIdx.x;
  const int lane = tid & 63;
  const int wv = tid >> 6;
  const int quad = lane >> 4;
  const int m15 = lane & 15;
  const long mBase = (long)blockIdx.y * 128;
  const int nBase = blockIdx.x * 64;

  f32x4 acc[2][4];
  #pragma unroll
  for (int r = 0; r < 2; ++r)
    #pragma unroll
    for (int c = 0; c < 4; ++c) acc[r][c] = (f32x4){0.f, 0.f, 0.f, 0.f};

  const int ar = tid >> 2;          // 0..63
  const int ak = (tid & 3) * 8;     // 0,8,16,24
  const ushort* Xg0 = X + (mBase + ar) * (long)lda + ak;
  const ushort* Xg1 = X + (mBase + 64 + ar) * (long)lda + ak;
  const ushort* Wg  = W + (long)(nBase + ar) * K + ak;
  ushort* Al0 = &Al[(size_t)tid * 8];   // wave-uniform base + lane*16B pattern
  ushort* Al1 = &Al[2048 + (size_t)tid * 8];
  ushort* Bl0 = &Bl[(size_t)tid * 8];

  for (int k0 = 0; k0 < K; k0 += 32) {
    __syncthreads();
    gload_lds16(Xg0 + k0, Al0);
    gload_lds16(Xg1 + k0, Al1);
    gload_lds16(Wg + k0, Bl0);
    __syncthreads();
    bf16x8 a0 = *(const bf16x8*)&Al[(wv * 32 + m15) * 32 + quad * 8];
    bf16x8 a1 = *(const bf16x8*)&Al[(wv * 32 + 16 + m15) * 32 + quad * 8];
    #pragma unroll
    for (int ct = 0; ct < 4; ++ct) {
      bf16x8 b = *(const bf16x8*)&Bl[(ct * 16 + m15) * 32 + quad * 8];
      acc[0][ct] = __builtin_amdgcn_mfma_f32_16x16x32_bf16(a0, b, acc[0][ct], 0, 0, 0);
      acc[1][ct] = __builtin_amdgcn_mfma_f32_16x16x32_bf16(a1, b, acc[1][ct], 0, 0, 0);
    }
  }
  // epilogue: C/D layout col=lane&15, row=(lane>>4)*4+i   [verified m89/m91]
  #pragma unroll
  for (int rt = 0; rt < 2; ++rt)
    #pragma unroll
    for (int ct = 0; ct < 4; ++ct)
      #pragma unroll
      for (int i = 0; i < 4; ++i) {
        long row = mBase + wv * 32 + rt * 16 + quad * 4 + i;
        int col = nBase + ct * 16 + m15;
        float v = acc[rt][ct][i] + bias[col];
        if (EPI == 1) {
          v += addin[row * N + col];
          ((float*)outp)[row * N + col] = v;
        } else {
          ((__hip_bfloat16*)outp)[row * N + col] = __float2bfloat16(v);
        }
      }
}

// -------- window attention: one block per 7x7 window, loop over 8 heads -----
// qkv: (Mc, 576) bf16 [q | k | v], q pre-scaled. ctx written IN-PLACE into the
// q slot (q dead once loaded to LDS; windows are block-exclusive).
__global__ __launch_bounds__(256) void attn_kernel(
    const float* __restrict__ rpe, __hip_bfloat16* __restrict__ qkv)
{
  __shared__ float q_l[49 * 25];   // pad 24->25
  __shared__ float k_l[49 * 25];
  __shared__ float v_l[49 * 25];
  __shared__ float S_l[49 * 50];
  const int wid = blockIdx.x;           // 0..CB*256-1
  const int b = wid >> 8;               // chunk-relative image
  const int wl = wid & 255;
  const int wh = wl >> 4;
  const int wwi = wl & 15;
  const int tid = threadIdx.x;

  for (int h = 0; h < 8; ++h) {
    for (int e = tid; e < 1176; e += 256) {   // 49 tokens * 24 dims
      int t = e / 24, d = e - t * 24;
      int py = t / 7, px = t - py * 7;
      long row = (long)b * 12544 + (wh * 7 + py) * 112 + (wwi * 7 + px);
      const __hip_bfloat16* base = qkv + row * 576 + h * 24 + d;
      q_l[t * 25 + d] = __bfloat162float(base[0]);
      k_l[t * 25 + d] = __bfloat162float(base[192]);
      v_l[t * 25 + d] = __bfloat162float(base[384]);
    }
    __syncthreads();
    for (int p = tid; p < 2401; p += 256) {   // S = q k^T + bias
      int i = p / 49, j = p - i * 49;
      float s = 0.f;
      #pragma unroll
      for (int d = 0; d < 24; ++d) s += q_l[i * 25 + d] * k_l[j * 25 + d];
      int yi = i / 7, xi = i - yi * 7, yj = j / 7, xj = j - yj * 7;
      int ridx = (yi - yj + 6) * 13 + (xi - xj + 6);
      s += rpe[ridx * 8 + h];
      S_l[i * 50 + j] = s;
    }
    __syncthreads();
    if (tid < 49) {                           // softmax over row tid
      float mx = -1e30f;
      for (int j = 0; j < 49; ++j) mx = fmaxf(mx, S_l[tid * 50 + j]);
      float sm = 0.f;
      for (int j = 0; j < 49; ++j) {
        float e = __expf(S_l[tid * 50 + j] - mx);
        S_l[tid * 50 + j] = e;
        sm += e;
      }
      float inv = 1.f / sm;
      for (int j = 0; j < 49; ++j) S_l[tid * 50 + j] *= inv;
    }
    __syncthreads();
    for (int p = tid; p < 1176; p += 256) {   // ctx = P v  -> q slot
      int t = p / 24, d = p - t * 24;
      float s = 0.f;
      #pragma unroll
      for (int j = 0; j < 49; ++j) s += S_l[t * 50 + j] * v_l[j * 25 + d];
      int py = t / 7, px = t - py * 7;
      long row = (long)b * 12544 + (wh * 7 + py) * 112 + (wwi * 7 + px);
      qkv[row * 576 + h * 24 + d] = __float2bfloat16(s);
    }
    __syncthreads();
  }
}

// -------- depthwise 3x3 conv (channels-last) + bias + exact GELU ------------
// grid: (3 channel-groups of 256, W=112, CB*H)
__global__ __launch_bounds__(256) void dwconv_gelu_kernel(
    const __hip_bfloat16* __restrict__ y1, const float* __restrict__ w,
    const float* __restrict__ bias, __hip_bfloat16* __restrict__ y2)
{
  const int c = blockIdx.x * 256 + threadIdx.x;  // 0..767
  const int wq = blockIdx.y;                     // 0..111
  const int bh = blockIdx.z;                     // 0..CB*112-1
  const int b = bh / 112;
  const int hq = bh - b * 112;
  float acc = bias[c];
  #pragma unroll
  for (int dy = -1; dy <= 1; ++dy) {
    int hh = hq + dy;
    if (hh < 0 || hh >= 112) continue;
    #pragma unroll
    for (int dx = -1; dx <= 1; ++dx) {
      int wp = wq + dx;
      if (wp < 0 || wp >= 112) continue;
      float wt = w[c * 9 + (dy + 1) * 3 + (dx + 1)];
      acc += wt * __bfloat162float(y1[((size_t)(b * 112 + hh) * 112 + wp) * HID + c]);
    }
  }
  float gl = 0.5f * acc * (1.0f + erff(acc * 0.70710678118654752f));
  y2[((size_t)(b * 112 + hq) * 112 + wq) * HID + c] = __float2bfloat16(gl);
}

// ---------------------------------------------------------------------------
extern "C" void kernel_launch(void* const* d_in, const int* in_sizes, int n_in,
                              void* d_out, int out_size, void* d_ws, size_t ws_size,
                              hipStream_t stream) {
  const float* x      = (const float*)d_in[0];
  const float* n1g    = (const float*)d_in[1];
  const float* n1b    = (const float*)d_in[2];
  const float* q_w    = (const float*)d_in[3];
  const float* q_b    = (const float*)d_in[4];
  const float* kv_w   = (const float*)d_in[5];
  const float* kv_b   = (const float*)d_in[6];
  const float* rpe    = (const float*)d_in[7];
  const float* proj_w = (const float*)d_in[8];
  const float* proj_b = (const float*)d_in[9];
  const float* n2g    = (const float*)d_in[10];
  const float* n2b    = (const float*)d_in[11];
  const float* fc1_w  = (const float*)d_in[12];
  const float* fc1_b  = (const float*)d_in[13];
  const float* dw_w   = (const float*)d_in[14];
  const float* dw_b   = (const float*)d_in[15];
  const float* fc2_w  = (const float*)d_in[16];
  const float* fc2_b  = (const float*)d_in[17];
  float* out = (float*)d_out;

  // ---- weights at front of ws (~0.9 MB) ----
  char* ws = (char*)d_ws;
  __hip_bfloat16* wcat  = (__hip_bfloat16*)(ws);               // 576*192 bf16
  __hip_bfloat16* projw = (__hip_bfloat16*)(ws + 221184);      // 192*192
  __hip_bfloat16* fc1w  = (__hip_bfloat16*)(ws + 294912);      // 768*192
  __hip_bfloat16* fc2w  = (__hip_bfloat16*)(ws + 589824);      // 192*768
  float* bcat           = (float*)(ws + 884736);               // 576 f32
  const size_t WOFF = 1u << 20;                                // 1 MB

  // ---- pick images-per-chunk CB so the activation buffers fit ws_size ----
  // peak/chunk = A (Mc*384 B) + B (Mc*1536 B) + C (Mc*1536 B) = Mc*3456 B
  int CB = 8;
  while (CB > 1 && WOFF + (size_t)CB * 12544 * 3456 > ws_size) CB >>= 1;
  const size_t Mc = (size_t)CB * 12544;          // tokens per chunk
  char* Abuf = ws + WOFF;                        // xn / yn   (bf16 Mc x 192)
  char* Bbuf = Abuf + Mc * 384;                  // qkv (Mc x 576) / y2 (Mc x 768)
  char* Cbuf = Bbuf + Mc * 1536;                 // y1 (bf16 Mc x 768)
  __hip_bfloat16* xn  = (__hip_bfloat16*)Abuf;
  __hip_bfloat16* qkv = (__hip_bfloat16*)Bbuf;
  __hip_bfloat16* y2  = (__hip_bfloat16*)Bbuf;
  __hip_bfloat16* y1  = (__hip_bfloat16*)Cbuf;

  prep_kernel<<<576, 256, 0, stream>>>(q_w, q_b, kv_w, kv_b, proj_w, fc1_w,
                                       fc2_w, wcat, bcat, projw, fc1w, fc2w);

  const int nChunks = 8 / CB;
  const int mt = CB * 98;                        // 128-row tiles per chunk
  for (int cchunk = 0; cchunk < nChunks; ++cchunk) {
    const size_t toff = (size_t)cchunk * Mc;     // token offset
    const float* xc = x + toff * C_DIM;
    float* oc = out + toff * C_DIM;

    ln_kernel<<<(int)(Mc / 4), 256, 0, stream>>>(xc, n1g, n1b, xn);
    gemm_kernel<0><<<dim3(9, mt), 256, 0, stream>>>(
        (const ushort*)xn, 192, (const ushort*)wcat, bcat, nullptr, qkv, 576, 192);
    attn_kernel<<<CB * 256, 256, 0, stream>>>(rpe, qkv);
    gemm_kernel<1><<<dim3(3, mt), 256, 0, stream>>>(
        (const ushort*)qkv, 576, (const ushort*)projw, proj_b, xc, oc, 192, 192);
    ln_kernel<<<(int)(Mc / 4), 256, 0, stream>>>(oc, n2g, n2b, xn);
    gemm_kernel<0><<<dim3(12, mt), 256, 0, stream>>>(
        (const ushort*)xn, 192, (const ushort*)fc1w, fc1_b, nullptr, y1, 768, 192);
    dwconv_gelu_kernel<<<dim3(3, 112, CB * 112), 256, 0, stream>>>(y1, dw_w, dw_b, y2);
    gemm_kernel<1><<<dim3(3, mt), 256, 0, stream>>>(
        (const ushort*)y2, 768, (const ushort*)fc2w, fc2_b, oc, oc, 192, 768);
  }
}

// Round 3
// 888.916 us; speedup vs baseline: 1.5862x; 1.5862x over previous
//
#include <hip/hip_runtime.h>
#include <hip/hip_bf16.h>
#include <cmath>

// Problem constants (B=8, H=W=112, C=192, heads=8, hd=24, ps=7, hid=768)
#define C_DIM 192
#define HID 768

typedef __attribute__((ext_vector_type(8))) __bf16 bf16x8;
typedef __attribute__((ext_vector_type(4))) float f32x4;

__device__ __forceinline__ void gload_lds16(const void* g, void* l) {
  __builtin_amdgcn_global_load_lds(
      (__attribute__((address_space(1))) void*)(const_cast<void*>(g)),
      (__attribute__((address_space(3))) void*)(l), 16, 0, 0);
}

__device__ __forceinline__ float bfu2f(ushort u) {
  return __uint_as_float((unsigned)u << 16);
}
__device__ __forceinline__ ushort f2bfu(float f) {
  __hip_bfloat16 h = __float2bfloat16(f);
  return *reinterpret_cast<ushort*>(&h);
}

// ---------------- prep: weights fp32 -> bf16 (+ fold q scale) ----------------
__global__ __launch_bounds__(256) void prep_kernel(
    const float* __restrict__ q_w, const float* __restrict__ q_b,
    const float* __restrict__ kv_w, const float* __restrict__ kv_b,
    const float* __restrict__ proj_w, const float* __restrict__ fc1_w,
    const float* __restrict__ fc2_w,
    __hip_bfloat16* __restrict__ wcat, float* __restrict__ bcat,
    __hip_bfloat16* __restrict__ projw, __hip_bfloat16* __restrict__ fc1w,
    __hip_bfloat16* __restrict__ fc2w)
{
  int idx = blockIdx.x * 256 + threadIdx.x;
  const float scale = 0.20412414523193154f;  // 24^-0.5
  if (idx < 110592) {  // 576 x 192 concat [q_w*scale ; kv_w]
    float v = (idx < 36864) ? q_w[idx] * scale : kv_w[idx - 36864];
    wcat[idx] = __float2bfloat16(v);
  }
  if (idx < 576) bcat[idx] = (idx < 192) ? q_b[idx] * scale : kv_b[idx - 192];
  if (idx < 36864) projw[idx] = __float2bfloat16(proj_w[idx]);
  if (idx < 147456) {
    fc1w[idx] = __float2bfloat16(fc1_w[idx]);
    fc2w[idx] = __float2bfloat16(fc2_w[idx]);
  }
}

// -------- LayerNorm fp32 -> bf16, one wave per token (192 = 64*3) -----------
__global__ __launch_bounds__(256) void ln_kernel(
    const float* __restrict__ x, const float* __restrict__ g,
    const float* __restrict__ b, __hip_bfloat16* __restrict__ out)
{
  int t = blockIdx.x * 4 + (threadIdx.x >> 6);
  int lane = threadIdx.x & 63;
  const float* xr = x + (size_t)t * C_DIM;
  float v0 = xr[lane], v1 = xr[lane + 64], v2 = xr[lane + 128];
  float s = v0 + v1 + v2;
  float sq = v0 * v0 + v1 * v1 + v2 * v2;
  #pragma unroll
  for (int off = 32; off > 0; off >>= 1) {
    s += __shfl_xor(s, off, 64);
    sq += __shfl_xor(sq, off, 64);
  }
  float mean = s * (1.0f / 192.0f);
  float var = sq * (1.0f / 192.0f) - mean * mean;
  float rstd = rsqrtf(var + 1e-5f);
  size_t o = (size_t)t * C_DIM;
  out[o + lane]       = __float2bfloat16((v0 - mean) * rstd * g[lane] + b[lane]);
  out[o + lane + 64]  = __float2bfloat16((v1 - mean) * rstd * g[lane + 64] + b[lane + 64]);
  out[o + lane + 128] = __float2bfloat16((v2 - mean) * rstd * g[lane + 128] + b[lane + 128]);
}

// -------- MFMA bf16 GEMM: out[M,N] = X[M,K](lda) @ W[N,K]^T + bias (+ add) --
template <int EPI>
__global__ __launch_bounds__(256) void gemm_kernel(
    const ushort* __restrict__ X, int lda, const ushort* __restrict__ W,
    const float* __restrict__ bias, const float* __restrict__ addin,
    void* __restrict__ outp, int N, int K)
{
  __shared__ __align__(16) ushort Al[128 * 32];
  __shared__ __align__(16) ushort Bl[64 * 32];
  const int tid = threadIdx.x;
  const int lane = tid & 63;
  const int wv = tid >> 6;
  const int quad = lane >> 4;
  const int m15 = lane & 15;
  const long mBase = (long)blockIdx.y * 128;
  const int nBase = blockIdx.x * 64;

  f32x4 acc[2][4];
  #pragma unroll
  for (int r = 0; r < 2; ++r)
    #pragma unroll
    for (int c = 0; c < 4; ++c) acc[r][c] = (f32x4){0.f, 0.f, 0.f, 0.f};

  const int ar = tid >> 2;          // 0..63
  const int ak = (tid & 3) * 8;     // 0,8,16,24
  const ushort* Xg0 = X + (mBase + ar) * (long)lda + ak;
  const ushort* Xg1 = X + (mBase + 64 + ar) * (long)lda + ak;
  const ushort* Wg  = W + (long)(nBase + ar) * K + ak;
  ushort* Al0 = &Al[(size_t)tid * 8];
  ushort* Al1 = &Al[2048 + (size_t)tid * 8];
  ushort* Bl0 = &Bl[(size_t)tid * 8];

  for (int k0 = 0; k0 < K; k0 += 32) {
    __syncthreads();
    gload_lds16(Xg0 + k0, Al0);
    gload_lds16(Xg1 + k0, Al1);
    gload_lds16(Wg + k0, Bl0);
    __syncthreads();
    bf16x8 a0 = *(const bf16x8*)&Al[(wv * 32 + m15) * 32 + quad * 8];
    bf16x8 a1 = *(const bf16x8*)&Al[(wv * 32 + 16 + m15) * 32 + quad * 8];
    #pragma unroll
    for (int ct = 0; ct < 4; ++ct) {
      bf16x8 b = *(const bf16x8*)&Bl[(ct * 16 + m15) * 32 + quad * 8];
      acc[0][ct] = __builtin_amdgcn_mfma_f32_16x16x32_bf16(a0, b, acc[0][ct], 0, 0, 0);
      acc[1][ct] = __builtin_amdgcn_mfma_f32_16x16x32_bf16(a1, b, acc[1][ct], 0, 0, 0);
    }
  }
  // epilogue: C/D layout col=lane&15, row=(lane>>4)*4+i   [verified m89/m91]
  #pragma unroll
  for (int rt = 0; rt < 2; ++rt)
    #pragma unroll
    for (int ct = 0; ct < 4; ++ct)
      #pragma unroll
      for (int i = 0; i < 4; ++i) {
        long row = mBase + wv * 32 + rt * 16 + quad * 4 + i;
        int col = nBase + ct * 16 + m15;
        float v = acc[rt][ct][i] + bias[col];
        if (EPI == 1) {
          v += addin[row * N + col];
          ((float*)outp)[row * N + col] = v;
        } else {
          ((__hip_bfloat16*)outp)[row * N + col] = __float2bfloat16(v);
        }
      }
}

// -------- window attention: one block per 7x7 window, loop over 8 heads -----
// qkv: (Mc, 576) bf16 [q | k | v], q pre-scaled. ctx written IN-PLACE into the
// q slot. All global I/O via ushort4 (4 channels at a time).
__global__ __launch_bounds__(256) void attn_kernel(
    const float* __restrict__ rpe, __hip_bfloat16* __restrict__ qkv)
{
  __shared__ float q_l[49 * 25];   // pad 24->25
  __shared__ float k_l[49 * 25];
  __shared__ float v_l[49 * 25];
  __shared__ float S_l[49 * 50];
  const int wid = blockIdx.x;
  const int b = wid >> 8;
  const int wl = wid & 255;
  const int wh = wl >> 4;
  const int wwi = wl & 15;
  const int tid = threadIdx.x;
  ushort* qkv_u = (ushort*)qkv;

  for (int h = 0; h < 8; ++h) {
    for (int e = tid; e < 294; e += 256) {    // 49 tokens * 6 ushort4 groups
      int t = e / 6, d4 = (e - t * 6) * 4;
      int py = t / 7, px = t - py * 7;
      long row = (long)b * 12544 + (wh * 7 + py) * 112 + (wwi * 7 + px);
      const ushort* base = qkv_u + row * 576 + h * 24 + d4;
      ushort4 qu = *(const ushort4*)(base);
      ushort4 ku = *(const ushort4*)(base + 192);
      ushort4 vu = *(const ushort4*)(base + 384);
      float* qd = &q_l[t * 25 + d4];
      float* kd = &k_l[t * 25 + d4];
      float* vd = &v_l[t * 25 + d4];
      qd[0] = bfu2f(qu.x); qd[1] = bfu2f(qu.y); qd[2] = bfu2f(qu.z); qd[3] = bfu2f(qu.w);
      kd[0] = bfu2f(ku.x); kd[1] = bfu2f(ku.y); kd[2] = bfu2f(ku.z); kd[3] = bfu2f(ku.w);
      vd[0] = bfu2f(vu.x); vd[1] = bfu2f(vu.y); vd[2] = bfu2f(vu.z); vd[3] = bfu2f(vu.w);
    }
    __syncthreads();
    for (int p = tid; p < 2401; p += 256) {   // S = q k^T + bias
      int i = p / 49, j = p - i * 49;
      float s = 0.f;
      #pragma unroll
      for (int d = 0; d < 24; ++d) s += q_l[i * 25 + d] * k_l[j * 25 + d];
      int yi = i / 7, xi = i - yi * 7, yj = j / 7, xj = j - yj * 7;
      int ridx = (yi - yj + 6) * 13 + (xi - xj + 6);
      s += rpe[ridx * 8 + h];
      S_l[i * 50 + j] = s;
    }
    __syncthreads();
    if (tid < 49) {                           // softmax over row tid
      float mx = -1e30f;
      for (int j = 0; j < 49; ++j) mx = fmaxf(mx, S_l[tid * 50 + j]);
      float sm = 0.f;
      for (int j = 0; j < 49; ++j) {
        float e = __expf(S_l[tid * 50 + j] - mx);
        S_l[tid * 50 + j] = e;
        sm += e;
      }
      float inv = 1.f / sm;
      for (int j = 0; j < 49; ++j) S_l[tid * 50 + j] *= inv;
    }
    __syncthreads();
    for (int p = tid; p < 294; p += 256) {    // ctx = P v  -> q slot
      int t = p / 6, d4 = (p - t * 6) * 4;
      float s0 = 0.f, s1 = 0.f, s2 = 0.f, s3 = 0.f;
      #pragma unroll
      for (int j = 0; j < 49; ++j) {
        float pj = S_l[t * 50 + j];
        const float* vr = &v_l[j * 25 + d4];
        s0 += pj * vr[0]; s1 += pj * vr[1]; s2 += pj * vr[2]; s3 += pj * vr[3];
      }
      int py = t / 7, px = t - py * 7;
      long row = (long)b * 12544 + (wh * 7 + py) * 112 + (wwi * 7 + px);
      ushort4 o;
      o.x = f2bfu(s0); o.y = f2bfu(s1); o.z = f2bfu(s2); o.w = f2bfu(s3);
      *(ushort4*)(qkv_u + row * 576 + h * 24 + d4) = o;
    }
    __syncthreads();
  }
}

// -------- depthwise 3x3 conv (channels-last) + bias + exact GELU ------------
// Register sliding window: 192 threads, thread owns 4 channels (ushort4) at
// fixed (b,w), sweeps 28 h-rows. 3 vector loads per output, pipelined 1 ahead.
// grid: (4 h-segments, W=112, CB images)
__global__ __launch_bounds__(192) void dwconv_gelu_kernel(
    const ushort* __restrict__ y1, const float* __restrict__ w,
    const float* __restrict__ bias, ushort* __restrict__ y2)
{
  const int t = threadIdx.x;           // 0..191
  const int c = t * 4;
  const int wq = blockIdx.y;           // 0..111
  const int b = blockIdx.z;
  const int h0 = blockIdx.x * 28;

  float wt[9][4];
  #pragma unroll
  for (int k = 0; k < 9; ++k)
    #pragma unroll
    for (int j = 0; j < 4; ++j) wt[k][j] = w[(c + j) * 9 + k];
  float bs[4];
  #pragma unroll
  for (int j = 0; j < 4; ++j) bs[j] = bias[c + j];

  const bool wl = (wq > 0), wr = (wq < 111);
  float r[3][3][4];   // [row: h-1,h,h+1][col: w-1,w,w+1][ch]
  float nx[3][4];

  auto loadrow = [&](int h, float dst[3][4]) {
    if (h < 0 || h >= 112) {
      #pragma unroll
      for (int x = 0; x < 3; ++x)
        #pragma unroll
        for (int j = 0; j < 4; ++j) dst[x][j] = 0.f;
      return;
    }
    const ushort* p = y1 + (((size_t)(b * 112 + h)) * 112 + wq) * HID + c;
    if (wl) {
      ushort4 u = *(const ushort4*)(p - HID);
      dst[0][0] = bfu2f(u.x); dst[0][1] = bfu2f(u.y);
      dst[0][2] = bfu2f(u.z); dst[0][3] = bfu2f(u.w);
    } else {
      dst[0][0] = dst[0][1] = dst[0][2] = dst[0][3] = 0.f;
    }
    {
      ushort4 u = *(const ushort4*)(p);
      dst[1][0] = bfu2f(u.x); dst[1][1] = bfu2f(u.y);
      dst[1][2] = bfu2f(u.z); dst[1][3] = bfu2f(u.w);
    }
    if (wr) {
      ushort4 u = *(const ushort4*)(p + HID);
      dst[2][0] = bfu2f(u.x); dst[2][1] = bfu2f(u.y);
      dst[2][2] = bfu2f(u.z); dst[2][3] = bfu2f(u.w);
    } else {
      dst[2][0] = dst[2][1] = dst[2][2] = dst[2][3] = 0.f;
    }
  };

  loadrow(h0 - 1, r[0]);
  loadrow(h0, r[1]);
  loadrow(h0 + 1, r[2]);

  for (int hh = 0; hh < 28; ++hh) {
    const int h = h0 + hh;
    loadrow(h + 2, nx);                 // prefetch next row (1 iter ahead)
    float acc[4];
    #pragma unroll
    for (int j = 0; j < 4; ++j) acc[j] = bs[j];
    #pragma unroll
    for (int dy = 0; dy < 3; ++dy)
      #pragma unroll
      for (int dx = 0; dx < 3; ++dx)
        #pragma unroll
        for (int j = 0; j < 4; ++j)
          acc[j] += wt[dy * 3 + dx][j] * r[dy][dx][j];
    ushort4 o;
    {
      float g0 = 0.5f * acc[0] * (1.0f + erff(acc[0] * 0.70710678f));
      float g1 = 0.5f * acc[1] * (1.0f + erff(acc[1] * 0.70710678f));
      float g2 = 0.5f * acc[2] * (1.0f + erff(acc[2] * 0.70710678f));
      float g3 = 0.5f * acc[3] * (1.0f + erff(acc[3] * 0.70710678f));
      o.x = f2bfu(g0); o.y = f2bfu(g1); o.z = f2bfu(g2); o.w = f2bfu(g3);
    }
    *(ushort4*)(y2 + (((size_t)(b * 112 + h)) * 112 + wq) * HID + c) = o;
    #pragma unroll
    for (int x = 0; x < 3; ++x)
      #pragma unroll
      for (int j = 0; j < 4; ++j) {
        r[0][x][j] = r[1][x][j];
        r[1][x][j] = r[2][x][j];
        r[2][x][j] = nx[x][j];
      }
  }
}

// ---------------------------------------------------------------------------
extern "C" void kernel_launch(void* const* d_in, const int* in_sizes, int n_in,
                              void* d_out, int out_size, void* d_ws, size_t ws_size,
                              hipStream_t stream) {
  const float* x      = (const float*)d_in[0];
  const float* n1g    = (const float*)d_in[1];
  const float* n1b    = (const float*)d_in[2];
  const float* q_w    = (const float*)d_in[3];
  const float* q_b    = (const float*)d_in[4];
  const float* kv_w   = (const float*)d_in[5];
  const float* kv_b   = (const float*)d_in[6];
  const float* rpe    = (const float*)d_in[7];
  const float* proj_w = (const float*)d_in[8];
  const float* proj_b = (const float*)d_in[9];
  const float* n2g    = (const float*)d_in[10];
  const float* n2b    = (const float*)d_in[11];
  const float* fc1_w  = (const float*)d_in[12];
  const float* fc1_b  = (const float*)d_in[13];
  const float* dw_w   = (const float*)d_in[14];
  const float* dw_b   = (const float*)d_in[15];
  const float* fc2_w  = (const float*)d_in[16];
  const float* fc2_b  = (const float*)d_in[17];
  float* out = (float*)d_out;

  // ---- weights at front of ws (~0.9 MB) ----
  char* ws = (char*)d_ws;
  __hip_bfloat16* wcat  = (__hip_bfloat16*)(ws);               // 576*192 bf16
  __hip_bfloat16* projw = (__hip_bfloat16*)(ws + 221184);      // 192*192
  __hip_bfloat16* fc1w  = (__hip_bfloat16*)(ws + 294912);      // 768*192
  __hip_bfloat16* fc2w  = (__hip_bfloat16*)(ws + 589824);      // 192*768
  float* bcat           = (float*)(ws + 884736);               // 576 f32
  const size_t WOFF = 1u << 20;                                // 1 MB

  // ---- pick images-per-chunk CB so the activation buffers fit ws_size ----
  int CB = 8;
  while (CB > 1 && WOFF + (size_t)CB * 12544 * 3456 > ws_size) CB >>= 1;
  const size_t Mc = (size_t)CB * 12544;
  char* Abuf = ws + WOFF;                        // xn / yn   (bf16 Mc x 192)
  char* Bbuf = Abuf + Mc * 384;                  // qkv (Mc x 576) / y2 (Mc x 768)
  char* Cbuf = Bbuf + Mc * 1536;                 // y1 (bf16 Mc x 768)
  __hip_bfloat16* xn  = (__hip_bfloat16*)Abuf;
  __hip_bfloat16* qkv = (__hip_bfloat16*)Bbuf;
  __hip_bfloat16* y2  = (__hip_bfloat16*)Bbuf;
  __hip_bfloat16* y1  = (__hip_bfloat16*)Cbuf;

  prep_kernel<<<576, 256, 0, stream>>>(q_w, q_b, kv_w, kv_b, proj_w, fc1_w,
                                       fc2_w, wcat, bcat, projw, fc1w, fc2w);

  const int nChunks = 8 / CB;
  const int mt = CB * 98;
  for (int cchunk = 0; cchunk < nChunks; ++cchunk) {
    const size_t toff = (size_t)cchunk * Mc;
    const float* xc = x + toff * C_DIM;
    float* oc = out + toff * C_DIM;

    ln_kernel<<<(int)(Mc / 4), 256, 0, stream>>>(xc, n1g, n1b, xn);
    gemm_kernel<0><<<dim3(9, mt), 256, 0, stream>>>(
        (const ushort*)xn, 192, (const ushort*)wcat, bcat, nullptr, qkv, 576, 192);
    attn_kernel<<<CB * 256, 256, 0, stream>>>(rpe, qkv);
    gemm_kernel<1><<<dim3(3, mt), 256, 0, stream>>>(
        (const ushort*)qkv, 576, (const ushort*)projw, proj_b, xc, oc, 192, 192);
    ln_kernel<<<(int)(Mc / 4), 256, 0, stream>>>(oc, n2g, n2b, xn);
    gemm_kernel<0><<<dim3(12, mt), 256, 0, stream>>>(
        (const ushort*)xn, 192, (const ushort*)fc1w, fc1_b, nullptr, y1, 768, 192);
    dwconv_gelu_kernel<<<dim3(4, 112, CB), 192, 0, stream>>>(
        (const ushort*)y1, dw_w, dw_b, (ushort*)y2);
    gemm_kernel<1><<<dim3(3, mt), 256, 0, stream>>>(
        (const ushort*)y2, 768, (const ushort*)fc2w, fc2_b, oc, oc, 192, 768);
  }
}

// Round 4
// 733.931 us; speedup vs baseline: 1.9212x; 1.2112x over previous
//
#include <hip/hip_runtime.h>
#include <hip/hip_bf16.h>
#include <cmath>

// Problem constants (B=8, H=W=112, C=192, heads=8, hd=24, ps=7, hid=768)
#define C_DIM 192
#define HID 768

typedef __attribute__((ext_vector_type(8))) __bf16 bf16x8;
typedef __attribute__((ext_vector_type(4))) float f32x4;

__device__ __forceinline__ void gload_lds16(const void* g, void* l) {
  __builtin_amdgcn_global_load_lds(
      (__attribute__((address_space(1))) void*)(const_cast<void*>(g)),
      (__attribute__((address_space(3))) void*)(l), 16, 0, 0);
}

__device__ __forceinline__ float bfu2f(ushort u) {
  return __uint_as_float((unsigned)u << 16);
}
__device__ __forceinline__ ushort f2bfu(float f) {
  __hip_bfloat16 h = __float2bfloat16(f);
  return *reinterpret_cast<ushort*>(&h);
}

// ---------------- prep: weights fp32 -> bf16 (+ fold q scale) ----------------
__global__ __launch_bounds__(256) void prep_kernel(
    const float* __restrict__ q_w, const float* __restrict__ q_b,
    const float* __restrict__ kv_w, const float* __restrict__ kv_b,
    const float* __restrict__ proj_w, const float* __restrict__ fc1_w,
    const float* __restrict__ fc2_w,
    __hip_bfloat16* __restrict__ wcat, float* __restrict__ bcat,
    __hip_bfloat16* __restrict__ projw, __hip_bfloat16* __restrict__ fc1w,
    __hip_bfloat16* __restrict__ fc2w)
{
  int idx = blockIdx.x * 256 + threadIdx.x;
  const float scale = 0.20412414523193154f;  // 24^-0.5
  if (idx < 110592) {  // 576 x 192 concat [q_w*scale ; kv_w]
    float v = (idx < 36864) ? q_w[idx] * scale : kv_w[idx - 36864];
    wcat[idx] = __float2bfloat16(v);
  }
  if (idx < 576) bcat[idx] = (idx < 192) ? q_b[idx] * scale : kv_b[idx - 192];
  if (idx < 36864) projw[idx] = __float2bfloat16(proj_w[idx]);
  if (idx < 147456) {
    fc1w[idx] = __float2bfloat16(fc1_w[idx]);
    fc2w[idx] = __float2bfloat16(fc2_w[idx]);
  }
}

// -------- LayerNorm fp32 -> bf16, one wave per token (192 = 64*3) -----------
__global__ __launch_bounds__(256) void ln_kernel(
    const float* __restrict__ x, const float* __restrict__ g,
    const float* __restrict__ b, __hip_bfloat16* __restrict__ out)
{
  int t = blockIdx.x * 4 + (threadIdx.x >> 6);
  int lane = threadIdx.x & 63;
  const float* xr = x + (size_t)t * C_DIM;
  float v0 = xr[lane], v1 = xr[lane + 64], v2 = xr[lane + 128];
  float s = v0 + v1 + v2;
  float sq = v0 * v0 + v1 * v1 + v2 * v2;
  #pragma unroll
  for (int off = 32; off > 0; off >>= 1) {
    s += __shfl_xor(s, off, 64);
    sq += __shfl_xor(sq, off, 64);
  }
  float mean = s * (1.0f / 192.0f);
  float var = sq * (1.0f / 192.0f) - mean * mean;
  float rstd = rsqrtf(var + 1e-5f);
  size_t o = (size_t)t * C_DIM;
  out[o + lane]       = __float2bfloat16((v0 - mean) * rstd * g[lane] + b[lane]);
  out[o + lane + 64]  = __float2bfloat16((v1 - mean) * rstd * g[lane + 64] + b[lane + 64]);
  out[o + lane + 128] = __float2bfloat16((v2 - mean) * rstd * g[lane + 128] + b[lane + 128]);
}

// -------- MFMA bf16 GEMM: out[M,N] = X[M,K](lda) @ W[N,K]^T + bias (+ add) --
template <int EPI>
__global__ __launch_bounds__(256) void gemm_kernel(
    const ushort* __restrict__ X, int lda, const ushort* __restrict__ W,
    const float* __restrict__ bias, const float* __restrict__ addin,
    void* __restrict__ outp, int N, int K)
{
  __shared__ __align__(16) ushort Al[128 * 32];
  __shared__ __align__(16) ushort Bl[64 * 32];
  const int tid = threadIdx.x;
  const int lane = tid & 63;
  const int wv = tid >> 6;
  const int quad = lane >> 4;
  const int m15 = lane & 15;
  const long mBase = (long)blockIdx.y * 128;
  const int nBase = blockIdx.x * 64;

  f32x4 acc[2][4];
  #pragma unroll
  for (int r = 0; r < 2; ++r)
    #pragma unroll
    for (int c = 0; c < 4; ++c) acc[r][c] = (f32x4){0.f, 0.f, 0.f, 0.f};

  const int ar = tid >> 2;          // 0..63
  const int ak = (tid & 3) * 8;     // 0,8,16,24
  const ushort* Xg0 = X + (mBase + ar) * (long)lda + ak;
  const ushort* Xg1 = X + (mBase + 64 + ar) * (long)lda + ak;
  const ushort* Wg  = W + (long)(nBase + ar) * K + ak;
  ushort* Al0 = &Al[(size_t)tid * 8];
  ushort* Al1 = &Al[2048 + (size_t)tid * 8];
  ushort* Bl0 = &Bl[(size_t)tid * 8];

  for (int k0 = 0; k0 < K; k0 += 32) {
    __syncthreads();
    gload_lds16(Xg0 + k0, Al0);
    gload_lds16(Xg1 + k0, Al1);
    gload_lds16(Wg + k0, Bl0);
    __syncthreads();
    bf16x8 a0 = *(const bf16x8*)&Al[(wv * 32 + m15) * 32 + quad * 8];
    bf16x8 a1 = *(const bf16x8*)&Al[(wv * 32 + 16 + m15) * 32 + quad * 8];
    #pragma unroll
    for (int ct = 0; ct < 4; ++ct) {
      bf16x8 b = *(const bf16x8*)&Bl[(ct * 16 + m15) * 32 + quad * 8];
      acc[0][ct] = __builtin_amdgcn_mfma_f32_16x16x32_bf16(a0, b, acc[0][ct], 0, 0, 0);
      acc[1][ct] = __builtin_amdgcn_mfma_f32_16x16x32_bf16(a1, b, acc[1][ct], 0, 0, 0);
    }
  }
  // epilogue: C/D layout col=lane&15, row=(lane>>4)*4+i   [verified m89/m91]
  #pragma unroll
  for (int rt = 0; rt < 2; ++rt)
    #pragma unroll
    for (int ct = 0; ct < 4; ++ct)
      #pragma unroll
      for (int i = 0; i < 4; ++i) {
        long row = mBase + wv * 32 + rt * 16 + quad * 4 + i;
        int col = nBase + ct * 16 + m15;
        float v = acc[rt][ct][i] + bias[col];
        if (EPI == 1) {
          v += addin[row * N + col];
          ((float*)outp)[row * N + col] = v;
        } else {
          ((__hip_bfloat16*)outp)[row * N + col] = __float2bfloat16(v);
        }
      }
}

// -------- window attention: ONE WAVE PER WINDOW-HEAD, barrier-free ----------
// qkv: (Mc, 576) bf16 [q | k | v], q pre-scaled. ctx written in-place into the
// q slot. Lane i (<49) owns S-row i in registers; k/v broadcast from
// wave-private LDS; softmax entirely in registers. One __syncthreads total.
__global__ __launch_bounds__(256) void attn_kernel(
    const float* __restrict__ rpe, __hip_bfloat16* __restrict__ qkv)
{
  // per-wave: k (49x24 f32) + v (49x24 f32) = 2352 floats; then 4x172 bias
  __shared__ float lds[4 * 2352 + 4 * 172];
  const int tid = threadIdx.x;
  const int lane = tid & 63;
  const int wv = tid >> 6;
  const int wh = blockIdx.x * 4 + wv;       // window-head id
  const int h = wh & 7;
  const int win = wh >> 3;
  const int b = win >> 8;
  const int wl = win & 255;
  const int whi = wl >> 4;
  const int wwi = wl & 15;
  ushort* qkv_u = (ushort*)qkv;
  float* kv_w = &lds[wv * 2352];            // k rows stride 24, v at +1176
  float* bias_w = &lds[4 * 2352 + wv * 172];

  const long rowbase = (long)b * 12544 + (long)(whi * 7) * 112 + wwi * 7;

  // ---- stage k,v (bf16 global -> f32 LDS) ----
  #pragma unroll
  for (int rnd = 0; rnd < 10; ++rnd) {
    int e = lane + rnd * 64;
    if (e < 588) {                          // 49 tokens * 12 ushort4 (6k+6v)
      int t = e / 12;
      int r = e - t * 12;
      int mat = r / 6;                      // 0 = k, 1 = v
      int d4 = (r - mat * 6) * 4;
      int py = t / 7, px = t - py * 7;
      long row = rowbase + py * 112 + px;
      ushort4 u = *(const ushort4*)(qkv_u + row * 576 + 192 + mat * 192 + h * 24 + d4);
      float* dst = kv_w + mat * 1176 + t * 24 + d4;
      dst[0] = bfu2f(u.x); dst[1] = bfu2f(u.y);
      dst[2] = bfu2f(u.z); dst[3] = bfu2f(u.w);
    }
  }
  // ---- stage this head's rpe slice ----
  for (int r = lane; r < 169; r += 64) bias_w[r] = rpe[r * 8 + h];
  __syncthreads();

  const int i = (lane < 49) ? lane : 48;
  const int yi = i / 7, xi = i - yi * 7;
  const int base_i = yi * 13 + xi + 84;     // + offset 84 folded in
  const long myrow = rowbase + yi * 112 + xi;

  // ---- q row -> registers ----
  float q[24];
  #pragma unroll
  for (int d4 = 0; d4 < 24; d4 += 4) {
    ushort4 u = *(const ushort4*)(qkv_u + myrow * 576 + h * 24 + d4);
    q[d4] = bfu2f(u.x); q[d4 + 1] = bfu2f(u.y);
    q[d4 + 2] = bfu2f(u.z); q[d4 + 3] = bfu2f(u.w);
  }

  // ---- S row = q . k_j + bias (registers) ----
  float s[49];
  #pragma unroll
  for (int j = 0; j < 49; ++j) {
    const int yj = j / 7, xj = j % 7;       // compile-time
    const int base_j = yj * 13 + xj;
    const float* kr = kv_w + j * 24;
    float acc = 0.f;
    #pragma unroll
    for (int d4 = 0; d4 < 24; d4 += 4) {
      f32x4 kk = *(const f32x4*)(kr + d4);  // uniform broadcast read
      acc += q[d4] * kk[0] + q[d4 + 1] * kk[1] + q[d4 + 2] * kk[2] + q[d4 + 3] * kk[3];
    }
    s[j] = acc + bias_w[base_i - base_j];
  }

  // ---- softmax in registers ----
  float mx = s[0];
  #pragma unroll
  for (int j = 1; j < 49; ++j) mx = fmaxf(mx, s[j]);
  float sm = 0.f;
  #pragma unroll
  for (int j = 0; j < 49; ++j) { s[j] = __expf(s[j] - mx); sm += s[j]; }
  const float inv = 1.f / sm;
  #pragma unroll
  for (int j = 0; j < 49; ++j) s[j] *= inv;

  // ---- ctx row = P . V ----
  float o[24];
  #pragma unroll
  for (int d = 0; d < 24; ++d) o[d] = 0.f;
  #pragma unroll
  for (int j = 0; j < 49; ++j) {
    const float p = s[j];
    const float* vr = kv_w + 1176 + j * 24;
    #pragma unroll
    for (int d4 = 0; d4 < 24; d4 += 4) {
      f32x4 vvv = *(const f32x4*)(vr + d4); // uniform broadcast read
      o[d4] += p * vvv[0]; o[d4 + 1] += p * vvv[1];
      o[d4 + 2] += p * vvv[2]; o[d4 + 3] += p * vvv[3];
    }
  }

  // ---- store ctx into q slot ----
  if (lane < 49) {
    #pragma unroll
    for (int d4 = 0; d4 < 24; d4 += 4) {
      ushort4 u;
      u.x = f2bfu(o[d4]); u.y = f2bfu(o[d4 + 1]);
      u.z = f2bfu(o[d4 + 2]); u.w = f2bfu(o[d4 + 3]);
      *(ushort4*)(qkv_u + myrow * 576 + h * 24 + d4) = u;
    }
  }
}

// -------- depthwise 3x3 conv (channels-last) + bias + exact GELU ------------
__global__ __launch_bounds__(192) void dwconv_gelu_kernel(
    const ushort* __restrict__ y1, const float* __restrict__ w,
    const float* __restrict__ bias, ushort* __restrict__ y2)
{
  const int t = threadIdx.x;           // 0..191
  const int c = t * 4;
  const int wq = blockIdx.y;           // 0..111
  const int b = blockIdx.z;
  const int h0 = blockIdx.x * 28;

  float wt[9][4];
  #pragma unroll
  for (int k = 0; k < 9; ++k)
    #pragma unroll
    for (int j = 0; j < 4; ++j) wt[k][j] = w[(c + j) * 9 + k];
  float bs[4];
  #pragma unroll
  for (int j = 0; j < 4; ++j) bs[j] = bias[c + j];

  const bool wl = (wq > 0), wr = (wq < 111);
  float r[3][3][4];
  float nx[3][4];

  auto loadrow = [&](int h, float dst[3][4]) {
    if (h < 0 || h >= 112) {
      #pragma unroll
      for (int x = 0; x < 3; ++x)
        #pragma unroll
        for (int j = 0; j < 4; ++j) dst[x][j] = 0.f;
      return;
    }
    const ushort* p = y1 + (((size_t)(b * 112 + h)) * 112 + wq) * HID + c;
    if (wl) {
      ushort4 u = *(const ushort4*)(p - HID);
      dst[0][0] = bfu2f(u.x); dst[0][1] = bfu2f(u.y);
      dst[0][2] = bfu2f(u.z); dst[0][3] = bfu2f(u.w);
    } else {
      dst[0][0] = dst[0][1] = dst[0][2] = dst[0][3] = 0.f;
    }
    {
      ushort4 u = *(const ushort4*)(p);
      dst[1][0] = bfu2f(u.x); dst[1][1] = bfu2f(u.y);
      dst[1][2] = bfu2f(u.z); dst[1][3] = bfu2f(u.w);
    }
    if (wr) {
      ushort4 u = *(const ushort4*)(p + HID);
      dst[2][0] = bfu2f(u.x); dst[2][1] = bfu2f(u.y);
      dst[2][2] = bfu2f(u.z); dst[2][3] = bfu2f(u.w);
    } else {
      dst[2][0] = dst[2][1] = dst[2][2] = dst[2][3] = 0.f;
    }
  };

  loadrow(h0 - 1, r[0]);
  loadrow(h0, r[1]);
  loadrow(h0 + 1, r[2]);

  for (int hh = 0; hh < 28; ++hh) {
    const int h = h0 + hh;
    loadrow(h + 2, nx);
    float acc[4];
    #pragma unroll
    for (int j = 0; j < 4; ++j) acc[j] = bs[j];
    #pragma unroll
    for (int dy = 0; dy < 3; ++dy)
      #pragma unroll
      for (int dx = 0; dx < 3; ++dx)
        #pragma unroll
        for (int j = 0; j < 4; ++j)
          acc[j] += wt[dy * 3 + dx][j] * r[dy][dx][j];
    ushort4 oo;
    {
      float g0 = 0.5f * acc[0] * (1.0f + erff(acc[0] * 0.70710678f));
      float g1 = 0.5f * acc[1] * (1.0f + erff(acc[1] * 0.70710678f));
      float g2 = 0.5f * acc[2] * (1.0f + erff(acc[2] * 0.70710678f));
      float g3 = 0.5f * acc[3] * (1.0f + erff(acc[3] * 0.70710678f));
      oo.x = f2bfu(g0); oo.y = f2bfu(g1); oo.z = f2bfu(g2); oo.w = f2bfu(g3);
    }
    *(ushort4*)(y2 + (((size_t)(b * 112 + h)) * 112 + wq) * HID + c) = oo;
    #pragma unroll
    for (int x = 0; x < 3; ++x)
      #pragma unroll
      for (int j = 0; j < 4; ++j) {
        r[0][x][j] = r[1][x][j];
        r[1][x][j] = r[2][x][j];
        r[2][x][j] = nx[x][j];
      }
  }
}

// ---------------------------------------------------------------------------
extern "C" void kernel_launch(void* const* d_in, const int* in_sizes, int n_in,
                              void* d_out, int out_size, void* d_ws, size_t ws_size,
                              hipStream_t stream) {
  const float* x      = (const float*)d_in[0];
  const float* n1g    = (const float*)d_in[1];
  const float* n1b    = (const float*)d_in[2];
  const float* q_w    = (const float*)d_in[3];
  const float* q_b    = (const float*)d_in[4];
  const float* kv_w   = (const float*)d_in[5];
  const float* kv_b   = (const float*)d_in[6];
  const float* rpe    = (const float*)d_in[7];
  const float* proj_w = (const float*)d_in[8];
  const float* proj_b = (const float*)d_in[9];
  const float* n2g    = (const float*)d_in[10];
  const float* n2b    = (const float*)d_in[11];
  const float* fc1_w  = (const float*)d_in[12];
  const float* fc1_b  = (const float*)d_in[13];
  const float* dw_w   = (const float*)d_in[14];
  const float* dw_b   = (const float*)d_in[15];
  const float* fc2_w  = (const float*)d_in[16];
  const float* fc2_b  = (const float*)d_in[17];
  float* out = (float*)d_out;

  // ---- weights at front of ws (~0.9 MB) ----
  char* ws = (char*)d_ws;
  __hip_bfloat16* wcat  = (__hip_bfloat16*)(ws);               // 576*192 bf16
  __hip_bfloat16* projw = (__hip_bfloat16*)(ws + 221184);      // 192*192
  __hip_bfloat16* fc1w  = (__hip_bfloat16*)(ws + 294912);      // 768*192
  __hip_bfloat16* fc2w  = (__hip_bfloat16*)(ws + 589824);      // 192*768
  float* bcat           = (float*)(ws + 884736);               // 576 f32
  const size_t WOFF = 1u << 20;                                // 1 MB

  // ---- pick images-per-chunk CB so the activation buffers fit ws_size ----
  int CB = 8;
  while (CB > 1 && WOFF + (size_t)CB * 12544 * 3456 > ws_size) CB >>= 1;
  const size_t Mc = (size_t)CB * 12544;
  char* Abuf = ws + WOFF;                        // xn / yn   (bf16 Mc x 192)
  char* Bbuf = Abuf + Mc * 384;                  // qkv (Mc x 576) / y2 (Mc x 768)
  char* Cbuf = Bbuf + Mc * 1536;                 // y1 (bf16 Mc x 768)
  __hip_bfloat16* xn  = (__hip_bfloat16*)Abuf;
  __hip_bfloat16* qkv = (__hip_bfloat16*)Bbuf;
  __hip_bfloat16* y2  = (__hip_bfloat16*)Bbuf;
  __hip_bfloat16* y1  = (__hip_bfloat16*)Cbuf;

  prep_kernel<<<576, 256, 0, stream>>>(q_w, q_b, kv_w, kv_b, proj_w, fc1_w,
                                       fc2_w, wcat, bcat, projw, fc1w, fc2w);

  const int nChunks = 8 / CB;
  const int mt = CB * 98;
  for (int cchunk = 0; cchunk < nChunks; ++cchunk) {
    const size_t toff = (size_t)cchunk * Mc;
    const float* xc = x + toff * C_DIM;
    float* oc = out + toff * C_DIM;

    ln_kernel<<<(int)(Mc / 4), 256, 0, stream>>>(xc, n1g, n1b, xn);
    gemm_kernel<0><<<dim3(9, mt), 256, 0, stream>>>(
        (const ushort*)xn, 192, (const ushort*)wcat, bcat, nullptr, qkv, 576, 192);
    attn_kernel<<<CB * 512, 256, 0, stream>>>(rpe, qkv);   // CB*2048 wh / 4 per block
    gemm_kernel<1><<<dim3(3, mt), 256, 0, stream>>>(
        (const ushort*)qkv, 576, (const ushort*)projw, proj_b, xc, oc, 192, 192);
    ln_kernel<<<(int)(Mc / 4), 256, 0, stream>>>(oc, n2g, n2b, xn);
    gemm_kernel<0><<<dim3(12, mt), 256, 0, stream>>>(
        (const ushort*)xn, 192, (const ushort*)fc1w, fc1_b, nullptr, y1, 768, 192);
    dwconv_gelu_kernel<<<dim3(4, 112, CB), 192, 0, stream>>>(
        (const ushort*)y1, dw_w, dw_b, (ushort*)y2);
    gemm_kernel<1><<<dim3(3, mt), 256, 0, stream>>>(
        (const ushort*)y2, 768, (const ushort*)fc2w, fc2_b, oc, oc, 192, 768);
  }
}

// Round 5
// 729.391 us; speedup vs baseline: 1.9331x; 1.0062x over previous
//
#include <hip/hip_runtime.h>
#include <hip/hip_bf16.h>
#include <cmath>

// Problem constants (B=8, H=W=112, C=192, heads=8, hd=24, ps=7, hid=768)
#define C_DIM 192
#define HID 768

typedef __attribute__((ext_vector_type(8))) __bf16 bf16x8;
typedef __attribute__((ext_vector_type(4))) float f32x4;

__device__ __forceinline__ void gload_lds16(const void* g, void* l) {
  __builtin_amdgcn_global_load_lds(
      (__attribute__((address_space(1))) void*)(const_cast<void*>(g)),
      (__attribute__((address_space(3))) void*)(l), 16, 0, 0);
}

__device__ __forceinline__ float bfu2f(ushort u) {
  return __uint_as_float((unsigned)u << 16);
}
__device__ __forceinline__ ushort f2bfu(float f) {
  __hip_bfloat16 h = __float2bfloat16(f);
  return *reinterpret_cast<ushort*>(&h);
}
// tanh-form GELU: x*sigmoid(1.5957691x + 0.0713548x^3); |err| ~3e-4 << bf16 ulp
__device__ __forceinline__ float fgelu(float x) {
  float z = x * (1.5957691216f + 0.071354816f * x * x);
  return x / (1.f + __expf(-z));
}

// ---------------- prep: weights fp32 -> bf16 (+ fold q scale) ----------------
__global__ __launch_bounds__(256) void prep_kernel(
    const float* __restrict__ q_w, const float* __restrict__ q_b,
    const float* __restrict__ kv_w, const float* __restrict__ kv_b,
    const float* __restrict__ proj_w, const float* __restrict__ fc1_w,
    const float* __restrict__ fc2_w,
    __hip_bfloat16* __restrict__ wcat, float* __restrict__ bcat,
    __hip_bfloat16* __restrict__ projw, __hip_bfloat16* __restrict__ fc1w,
    __hip_bfloat16* __restrict__ fc2w)
{
  int idx = blockIdx.x * 256 + threadIdx.x;
  const float scale = 0.20412414523193154f;  // 24^-0.5
  if (idx < 110592) {
    float v = (idx < 36864) ? q_w[idx] * scale : kv_w[idx - 36864];
    wcat[idx] = __float2bfloat16(v);
  }
  if (idx < 576) bcat[idx] = (idx < 192) ? q_b[idx] * scale : kv_b[idx - 192];
  if (idx < 36864) projw[idx] = __float2bfloat16(proj_w[idx]);
  if (idx < 147456) {
    fc1w[idx] = __float2bfloat16(fc1_w[idx]);
    fc2w[idx] = __float2bfloat16(fc2_w[idx]);
  }
}

// -------- LayerNorm fp32 -> bf16, one wave per token (192 = 64*3) -----------
__global__ __launch_bounds__(256) void ln_kernel(
    const float* __restrict__ x, const float* __restrict__ g,
    const float* __restrict__ b, __hip_bfloat16* __restrict__ out)
{
  int t = blockIdx.x * 4 + (threadIdx.x >> 6);
  int lane = threadIdx.x & 63;
  const float* xr = x + (size_t)t * C_DIM;
  float v0 = xr[lane], v1 = xr[lane + 64], v2 = xr[lane + 128];
  float s = v0 + v1 + v2;
  float sq = v0 * v0 + v1 * v1 + v2 * v2;
  #pragma unroll
  for (int off = 32; off > 0; off >>= 1) {
    s += __shfl_xor(s, off, 64);
    sq += __shfl_xor(sq, off, 64);
  }
  float mean = s * (1.0f / 192.0f);
  float var = sq * (1.0f / 192.0f) - mean * mean;
  float rstd = rsqrtf(var + 1e-5f);
  size_t o = (size_t)t * C_DIM;
  out[o + lane]       = __float2bfloat16((v0 - mean) * rstd * g[lane] + b[lane]);
  out[o + lane + 64]  = __float2bfloat16((v1 - mean) * rstd * g[lane + 64] + b[lane + 64]);
  out[o + lane + 128] = __float2bfloat16((v2 - mean) * rstd * g[lane + 128] + b[lane + 128]);
}

// -------- MFMA bf16 GEMM, BK=96: out[M,N] = X[M,K](lda) @ W[N,K]^T + bias ---
// Block tile 128x64, 256 threads. Per 96-K chunk: stage A 128x96 + B 64x96
// (36.9 KB LDS, 4 blocks/CU), 9 global_load_lds dwordx4 per thread, then
// 3 k-steps x 8 MFMA without barriers. Chunk swizzle: slot cs holds global
// chunk (cs - off) mod 12, off = 2*(row&3) + ((row>>2)&1)  -> ds_read_b128
// windows tile all 32 banks 2-way (free).
// EPI 0: bf16 store (acc+bias).  EPI 1: fp32 store (acc+bias+addin).
template <int EPI>
__global__ __launch_bounds__(256) void gemm_kernel(
    const ushort* __restrict__ X, int lda, const ushort* __restrict__ W,
    const float* __restrict__ bias, const float* __restrict__ addin,
    void* __restrict__ outp, int N, int K)
{
  __shared__ __align__(16) ushort Al[128 * 96];
  __shared__ __align__(16) ushort Bl[64 * 96];
  const int tid = threadIdx.x;
  const int lane = tid & 63;
  const int wv = tid >> 6;
  const int quad = lane >> 4;
  const int m15 = lane & 15;
  const long mBase = (long)blockIdx.y * 128;
  const int nBase = blockIdx.x * 64;
  // lane-constant read swizzle offset (same for all rows this lane touches)
  const int offr = 2 * (m15 & 3) + ((m15 >> 2) & 1);

  f32x4 acc[2][4];
  #pragma unroll
  for (int r = 0; r < 2; ++r)
    #pragma unroll
    for (int c = 0; c < 4; ++c) acc[r][c] = (f32x4){0.f, 0.f, 0.f, 0.f};

  for (int kc0 = 0; kc0 < K; kc0 += 96) {
    __syncthreads();
    #pragma unroll
    for (int r = 0; r < 6; ++r) {          // A: 1536 slots of 16B
      int sI = tid + r * 256;
      int row = sI / 12;
      int cs = sI - row * 12;
      int off = 2 * (row & 3) + ((row >> 2) & 1);
      int gc = cs - off; if (gc < 0) gc += 12;
      gload_lds16(X + (mBase + row) * (long)lda + kc0 + gc * 8, Al + sI * 8);
    }
    #pragma unroll
    for (int r = 0; r < 3; ++r) {          // B: 768 slots of 16B
      int sI = tid + r * 256;
      int row = sI / 12;
      int cs = sI - row * 12;
      int off = 2 * (row & 3) + ((row >> 2) & 1);
      int gc = cs - off; if (gc < 0) gc += 12;
      gload_lds16(W + (long)(nBase + row) * K + kc0 + gc * 8, Bl + sI * 8);
    }
    __syncthreads();
    #pragma unroll
    for (int ks = 0; ks < 3; ++ks) {
      int cs = ks * 4 + quad + offr; if (cs >= 12) cs -= 12;
      bf16x8 a0 = *(const bf16x8*)&Al[(wv * 32 + m15) * 96 + cs * 8];
      bf16x8 a1 = *(const bf16x8*)&Al[(wv * 32 + 16 + m15) * 96 + cs * 8];
      #pragma unroll
      for (int ct = 0; ct < 4; ++ct) {
        bf16x8 b = *(const bf16x8*)&Bl[(ct * 16 + m15) * 96 + cs * 8];
        acc[0][ct] = __builtin_amdgcn_mfma_f32_16x16x32_bf16(a0, b, acc[0][ct], 0, 0, 0);
        acc[1][ct] = __builtin_amdgcn_mfma_f32_16x16x32_bf16(a1, b, acc[1][ct], 0, 0, 0);
      }
    }
  }
  // epilogue: C/D layout col=lane&15, row=(lane>>4)*4+i   [verified m89/m91]
  #pragma unroll
  for (int rt = 0; rt < 2; ++rt)
    #pragma unroll
    for (int ct = 0; ct < 4; ++ct)
      #pragma unroll
      for (int i = 0; i < 4; ++i) {
        long row = mBase + wv * 32 + rt * 16 + quad * 4 + i;
        int col = nBase + ct * 16 + m15;
        float v = acc[rt][ct][i] + bias[col];
        if (EPI == 1) {
          v += addin[row * N + col];
          ((float*)outp)[row * N + col] = v;
        } else {
          ((__hip_bfloat16*)outp)[row * N + col] = __float2bfloat16(v);
        }
      }
}

// -------- window attention: ONE WAVE PER WINDOW-HEAD, barrier-free ----------
__global__ __launch_bounds__(256) void attn_kernel(
    const float* __restrict__ rpe, __hip_bfloat16* __restrict__ qkv)
{
  __shared__ float lds[4 * 2352 + 4 * 172];
  const int tid = threadIdx.x;
  const int lane = tid & 63;
  const int wv = tid >> 6;
  const int wh = blockIdx.x * 4 + wv;
  const int h = wh & 7;
  const int win = wh >> 3;
  const int b = win >> 8;
  const int wl = win & 255;
  const int whi = wl >> 4;
  const int wwi = wl & 15;
  ushort* qkv_u = (ushort*)qkv;
  float* kv_w = &lds[wv * 2352];
  float* bias_w = &lds[4 * 2352 + wv * 172];

  const long rowbase = (long)b * 12544 + (long)(whi * 7) * 112 + wwi * 7;

  #pragma unroll
  for (int rnd = 0; rnd < 10; ++rnd) {
    int e = lane + rnd * 64;
    if (e < 588) {
      int t = e / 12;
      int r = e - t * 12;
      int mat = r / 6;
      int d4 = (r - mat * 6) * 4;
      int py = t / 7, px = t - py * 7;
      long row = rowbase + py * 112 + px;
      ushort4 u = *(const ushort4*)(qkv_u + row * 576 + 192 + mat * 192 + h * 24 + d4);
      float* dst = kv_w + mat * 1176 + t * 24 + d4;
      dst[0] = bfu2f(u.x); dst[1] = bfu2f(u.y);
      dst[2] = bfu2f(u.z); dst[3] = bfu2f(u.w);
    }
  }
  for (int r = lane; r < 169; r += 64) bias_w[r] = rpe[r * 8 + h];
  __syncthreads();

  const int i = (lane < 49) ? lane : 48;
  const int yi = i / 7, xi = i - yi * 7;
  const int base_i = yi * 13 + xi + 84;
  const long myrow = rowbase + yi * 112 + xi;

  float q[24];
  #pragma unroll
  for (int d4 = 0; d4 < 24; d4 += 4) {
    ushort4 u = *(const ushort4*)(qkv_u + myrow * 576 + h * 24 + d4);
    q[d4] = bfu2f(u.x); q[d4 + 1] = bfu2f(u.y);
    q[d4 + 2] = bfu2f(u.z); q[d4 + 3] = bfu2f(u.w);
  }

  float s[49];
  #pragma unroll
  for (int j = 0; j < 49; ++j) {
    const int yj = j / 7, xj = j % 7;
    const int base_j = yj * 13 + xj;
    const float* kr = kv_w + j * 24;
    float acc = 0.f;
    #pragma unroll
    for (int d4 = 0; d4 < 24; d4 += 4) {
      f32x4 kk = *(const f32x4*)(kr + d4);
      acc += q[d4] * kk[0] + q[d4 + 1] * kk[1] + q[d4 + 2] * kk[2] + q[d4 + 3] * kk[3];
    }
    s[j] = acc + bias_w[base_i - base_j];
  }

  float mx = s[0];
  #pragma unroll
  for (int j = 1; j < 49; ++j) mx = fmaxf(mx, s[j]);
  float sm = 0.f;
  #pragma unroll
  for (int j = 0; j < 49; ++j) { s[j] = __expf(s[j] - mx); sm += s[j]; }
  const float inv = 1.f / sm;
  #pragma unroll
  for (int j = 0; j < 49; ++j) s[j] *= inv;

  float o[24];
  #pragma unroll
  for (int d = 0; d < 24; ++d) o[d] = 0.f;
  #pragma unroll
  for (int j = 0; j < 49; ++j) {
    const float p = s[j];
    const float* vr = kv_w + 1176 + j * 24;
    #pragma unroll
    for (int d4 = 0; d4 < 24; d4 += 4) {
      f32x4 vvv = *(const f32x4*)(vr + d4);
      o[d4] += p * vvv[0]; o[d4 + 1] += p * vvv[1];
      o[d4 + 2] += p * vvv[2]; o[d4 + 3] += p * vvv[3];
    }
  }

  if (lane < 49) {
    #pragma unroll
    for (int d4 = 0; d4 < 24; d4 += 4) {
      ushort4 u;
      u.x = f2bfu(o[d4]); u.y = f2bfu(o[d4 + 1]);
      u.z = f2bfu(o[d4 + 2]); u.w = f2bfu(o[d4 + 3]);
      *(ushort4*)(qkv_u + myrow * 576 + h * 24 + d4) = u;
    }
  }
}

// -------- depthwise 3x3 conv (channels-last) + bias + tanh-GELU -------------
// 4 output rows per macro-iteration: 12 row-loads issued back-to-back for
// latency amortization. Thread owns 4 channels at fixed (b,w), 28 h-rows.
__global__ __launch_bounds__(192) void dwconv_gelu_kernel(
    const ushort* __restrict__ y1, const float* __restrict__ w,
    const float* __restrict__ bias, ushort* __restrict__ y2)
{
  const int t = threadIdx.x;           // 0..191
  const int c = t * 4;
  const int wq = blockIdx.y;           // 0..111
  const int b = blockIdx.z;
  const int h0 = blockIdx.x * 28;

  float wt[9][4];
  #pragma unroll
  for (int k = 0; k < 9; ++k)
    #pragma unroll
    for (int j = 0; j < 4; ++j) wt[k][j] = w[(c + j) * 9 + k];
  float bs[4];
  #pragma unroll
  for (int j = 0; j < 4; ++j) bs[j] = bias[c + j];

  const bool wlf = (wq > 0), wrf = (wq < 111);
  float rb[6][3][4];   // rows rel-1..rel+4, cols w-1..w+1, 4 ch

  auto loadrow = [&](int h, float dst[3][4]) {
    if (h < 0 || h >= 112) {
      #pragma unroll
      for (int x = 0; x < 3; ++x)
        #pragma unroll
        for (int j = 0; j < 4; ++j) dst[x][j] = 0.f;
      return;
    }
    const ushort* p = y1 + (((size_t)(b * 112 + h)) * 112 + wq) * HID + c;
    if (wlf) {
      ushort4 u = *(const ushort4*)(p - HID);
      dst[0][0] = bfu2f(u.x); dst[0][1] = bfu2f(u.y);
      dst[0][2] = bfu2f(u.z); dst[0][3] = bfu2f(u.w);
    } else {
      dst[0][0] = dst[0][1] = dst[0][2] = dst[0][3] = 0.f;
    }
    {
      ushort4 u = *(const ushort4*)(p);
      dst[1][0] = bfu2f(u.x); dst[1][1] = bfu2f(u.y);
      dst[1][2] = bfu2f(u.z); dst[1][3] = bfu2f(u.w);
    }
    if (wrf) {
      ushort4 u = *(const ushort4*)(p + HID);
      dst[2][0] = bfu2f(u.x); dst[2][1] = bfu2f(u.y);
      dst[2][2] = bfu2f(u.z); dst[2][3] = bfu2f(u.w);
    } else {
      dst[2][0] = dst[2][1] = dst[2][2] = dst[2][3] = 0.f;
    }
  };

  loadrow(h0 - 1, rb[0]);
  loadrow(h0, rb[1]);

  for (int m = 0; m < 7; ++m) {
    const int hb = h0 + m * 4;
    loadrow(hb + 1, rb[2]);
    loadrow(hb + 2, rb[3]);
    loadrow(hb + 3, rb[4]);
    loadrow(hb + 4, rb[5]);
    #pragma unroll
    for (int o = 0; o < 4; ++o) {
      float acc[4];
      #pragma unroll
      for (int j = 0; j < 4; ++j) acc[j] = bs[j];
      #pragma unroll
      for (int dy = 0; dy < 3; ++dy)
        #pragma unroll
        for (int dx = 0; dx < 3; ++dx)
          #pragma unroll
          for (int j = 0; j < 4; ++j)
            acc[j] += wt[dy * 3 + dx][j] * rb[o + dy][dx][j];
      ushort4 oo;
      oo.x = f2bfu(fgelu(acc[0])); oo.y = f2bfu(fgelu(acc[1]));
      oo.z = f2bfu(fgelu(acc[2])); oo.w = f2bfu(fgelu(acc[3]));
      *(ushort4*)(y2 + (((size_t)(b * 112 + hb + o)) * 112 + wq) * HID + c) = oo;
    }
    #pragma unroll
    for (int x = 0; x < 3; ++x)
      #pragma unroll
      for (int j = 0; j < 4; ++j) {
        rb[0][x][j] = rb[4][x][j];
        rb[1][x][j] = rb[5][x][j];
      }
  }
}

// ---------------------------------------------------------------------------
extern "C" void kernel_launch(void* const* d_in, const int* in_sizes, int n_in,
                              void* d_out, int out_size, void* d_ws, size_t ws_size,
                              hipStream_t stream) {
  const float* x      = (const float*)d_in[0];
  const float* n1g    = (const float*)d_in[1];
  const float* n1b    = (const float*)d_in[2];
  const float* q_w    = (const float*)d_in[3];
  const float* q_b    = (const float*)d_in[4];
  const float* kv_w   = (const float*)d_in[5];
  const float* kv_b   = (const float*)d_in[6];
  const float* rpe    = (const float*)d_in[7];
  const float* proj_w = (const float*)d_in[8];
  const float* proj_b = (const float*)d_in[9];
  const float* n2g    = (const float*)d_in[10];
  const float* n2b    = (const float*)d_in[11];
  const float* fc1_w  = (const float*)d_in[12];
  const float* fc1_b  = (const float*)d_in[13];
  const float* dw_w   = (const float*)d_in[14];
  const float* dw_b   = (const float*)d_in[15];
  const float* fc2_w  = (const float*)d_in[16];
  const float* fc2_b  = (const float*)d_in[17];
  float* out = (float*)d_out;

  // ---- weights at front of ws (~0.9 MB) ----
  char* ws = (char*)d_ws;
  __hip_bfloat16* wcat  = (__hip_bfloat16*)(ws);               // 576*192 bf16
  __hip_bfloat16* projw = (__hip_bfloat16*)(ws + 221184);      // 192*192
  __hip_bfloat16* fc1w  = (__hip_bfloat16*)(ws + 294912);      // 768*192
  __hip_bfloat16* fc2w  = (__hip_bfloat16*)(ws + 589824);      // 192*768
  float* bcat           = (float*)(ws + 884736);               // 576 f32
  const size_t WOFF = 1u << 20;                                // 1 MB

  // ---- pick images-per-chunk CB so the activation buffers fit ws_size ----
  int CB = 8;
  while (CB > 1 && WOFF + (size_t)CB * 12544 * 3456 > ws_size) CB >>= 1;
  const size_t Mc = (size_t)CB * 12544;
  char* Abuf = ws + WOFF;                        // xn / yn   (bf16 Mc x 192)
  char* Bbuf = Abuf + Mc * 384;                  // qkv (Mc x 576) / y2 (Mc x 768)
  char* Cbuf = Bbuf + Mc * 1536;                 // y1 (bf16 Mc x 768)
  __hip_bfloat16* xn  = (__hip_bfloat16*)Abuf;
  __hip_bfloat16* qkv = (__hip_bfloat16*)Bbuf;
  __hip_bfloat16* y2  = (__hip_bfloat16*)Bbuf;
  __hip_bfloat16* y1  = (__hip_bfloat16*)Cbuf;

  prep_kernel<<<576, 256, 0, stream>>>(q_w, q_b, kv_w, kv_b, proj_w, fc1_w,
                                       fc2_w, wcat, bcat, projw, fc1w, fc2w);

  const int nChunks = 8 / CB;
  const int mt = CB * 98;
  for (int cchunk = 0; cchunk < nChunks; ++cchunk) {
    const size_t toff = (size_t)cchunk * Mc;
    const float* xc = x + toff * C_DIM;
    float* oc = out + toff * C_DIM;

    ln_kernel<<<(int)(Mc / 4), 256, 0, stream>>>(xc, n1g, n1b, xn);
    gemm_kernel<0><<<dim3(9, mt), 256, 0, stream>>>(
        (const ushort*)xn, 192, (const ushort*)wcat, bcat, nullptr, qkv, 576, 192);
    attn_kernel<<<CB * 512, 256, 0, stream>>>(rpe, qkv);
    gemm_kernel<1><<<dim3(3, mt), 256, 0, stream>>>(
        (const ushort*)qkv, 576, (const ushort*)projw, proj_b, xc, oc, 192, 192);
    ln_kernel<<<(int)(Mc / 4), 256, 0, stream>>>(oc, n2g, n2b, xn);
    gemm_kernel<0><<<dim3(12, mt), 256, 0, stream>>>(
        (const ushort*)xn, 192, (const ushort*)fc1w, fc1_b, nullptr, y1, 768, 192);
    dwconv_gelu_kernel<<<dim3(4, 112, CB), 192, 0, stream>>>(
        (const ushort*)y1, dw_w, dw_b, (ushort*)y2);
    gemm_kernel<1><<<dim3(3, mt), 256, 0, stream>>>(
        (const ushort*)y2, 768, (const ushort*)fc2w, fc2_b, oc, oc, 192, 768);
  }
}

// Round 6
// 667.683 us; speedup vs baseline: 2.1118x; 1.0924x over previous
//
#include <hip/hip_runtime.h>
#include <hip/hip_bf16.h>
#include <cmath>

// Problem constants (B=8, H=W=112, C=192, heads=8, hd=24, ps=7, hid=768)
#define C_DIM 192
#define HID 768

typedef __attribute__((ext_vector_type(8))) __bf16 bf16x8;
typedef __attribute__((ext_vector_type(4))) float f32x4;

__device__ __forceinline__ void gload_lds16(const void* g, void* l) {
  __builtin_amdgcn_global_load_lds(
      (__attribute__((address_space(1))) void*)(const_cast<void*>(g)),
      (__attribute__((address_space(3))) void*)(l), 16, 0, 0);
}

__device__ __forceinline__ float bfu2f(ushort u) {
  return __uint_as_float((unsigned)u << 16);
}
__device__ __forceinline__ ushort f2bfu(float f) {
  __hip_bfloat16 h = __float2bfloat16(f);
  return *reinterpret_cast<ushort*>(&h);
}
// tanh-form GELU: |err| ~3e-4 << bf16 ulp (validated R5, absmax 0.0156)
__device__ __forceinline__ float fgelu(float x) {
  float z = x * (1.5957691216f + 0.071354816f * x * x);
  return x / (1.f + __expf(-z));
}

// ---------------- prep: weights fp32 -> bf16 (+ fold q scale) ----------------
__global__ __launch_bounds__(256) void prep_kernel(
    const float* __restrict__ q_w, const float* __restrict__ q_b,
    const float* __restrict__ kv_w, const float* __restrict__ kv_b,
    const float* __restrict__ proj_w, const float* __restrict__ fc1_w,
    const float* __restrict__ fc2_w,
    __hip_bfloat16* __restrict__ wcat, float* __restrict__ bcat,
    __hip_bfloat16* __restrict__ projw, __hip_bfloat16* __restrict__ fc1w,
    __hip_bfloat16* __restrict__ fc2w)
{
  int idx = blockIdx.x * 256 + threadIdx.x;
  const float scale = 0.20412414523193154f;  // 24^-0.5
  if (idx < 110592) {
    float v = (idx < 36864) ? q_w[idx] * scale : kv_w[idx - 36864];
    wcat[idx] = __float2bfloat16(v);
  }
  if (idx < 576) bcat[idx] = (idx < 192) ? q_b[idx] * scale : kv_b[idx - 192];
  if (idx < 36864) projw[idx] = __float2bfloat16(proj_w[idx]);
  if (idx < 147456) {
    fc1w[idx] = __float2bfloat16(fc1_w[idx]);
    fc2w[idx] = __float2bfloat16(fc2_w[idx]);
  }
}

// -------- LayerNorm fp32 -> bf16, one wave per token (192 = 64*3) -----------
__global__ __launch_bounds__(256) void ln_kernel(
    const float* __restrict__ x, const float* __restrict__ g,
    const float* __restrict__ b, __hip_bfloat16* __restrict__ out)
{
  int t = blockIdx.x * 4 + (threadIdx.x >> 6);
  int lane = threadIdx.x & 63;
  const float* xr = x + (size_t)t * C_DIM;
  float v0 = xr[lane], v1 = xr[lane + 64], v2 = xr[lane + 128];
  float s = v0 + v1 + v2;
  float sq = v0 * v0 + v1 * v1 + v2 * v2;
  #pragma unroll
  for (int off = 32; off > 0; off >>= 1) {
    s += __shfl_xor(s, off, 64);
    sq += __shfl_xor(sq, off, 64);
  }
  float mean = s * (1.0f / 192.0f);
  float var = sq * (1.0f / 192.0f) - mean * mean;
  float rstd = rsqrtf(var + 1e-5f);
  size_t o = (size_t)t * C_DIM;
  out[o + lane]       = __float2bfloat16((v0 - mean) * rstd * g[lane] + b[lane]);
  out[o + lane + 64]  = __float2bfloat16((v1 - mean) * rstd * g[lane + 64] + b[lane + 64]);
  out[o + lane + 128] = __float2bfloat16((v2 - mean) * rstd * g[lane + 128] + b[lane + 128]);
}

// ===== GEMM variant A: K=192, A-tile LDS-resident, serial n-tiles ===========
// out[M,N] = X[M,192](lda) @ W[N,192]^T + bias (+addin).  A staged to LDS
// ONCE per block (vector-port traffic = A bytes exactly); per n-tile: stage
// 64x192 B, 48 MFMA, epilogue.  24-slot rotation swizzle: physical col-slot
// cs of row r holds logical chunk (cs - r) mod 24 -> b128 reads <=2-way banks.
template <int EPI>
__global__ __launch_bounds__(256) void gemmA_kernel(
    const ushort* __restrict__ X, int lda, const ushort* __restrict__ W,
    const float* __restrict__ bias, const float* __restrict__ addin,
    void* __restrict__ outp, int N)
{
  __shared__ __align__(16) ushort Al[128 * 192];  // 49152 B
  __shared__ __align__(16) ushort Bl[64 * 192];   // 24576 B
  const int tid = threadIdx.x;
  const int lane = tid & 63;
  const int wv = tid >> 6;
  const int quad = lane >> 4;
  const int m15 = lane & 15;
  const long mBase = (long)blockIdx.y * 128;
  const int NT = N >> 6;

  // ---- stage A once: 3072 slots of 16B, 12 per thread ----
  #pragma unroll
  for (int r = 0; r < 12; ++r) {
    int sI = tid + r * 256;
    int row = sI / 24;
    int cs = sI - row * 24;
    int gc = cs - (row % 24); if (gc < 0) gc += 24;
    gload_lds16(X + (mBase + row) * (long)lda + gc * 8, Al + sI * 8);
  }

  const int rA0 = wv * 32 + m15, rA1 = rA0 + 16;
  const int rA0m = rA0 % 24, rA1m = rA1 % 24;

  for (int nt = 0; nt < NT; ++nt) {
    __syncthreads();   // prior n-tile's B reads done (and A/B stores drained)
    #pragma unroll
    for (int r = 0; r < 6; ++r) {       // stage B n-tile: 1536 slots
      int sI = tid + r * 256;
      int row = sI / 24;
      int cs = sI - row * 24;
      int gc = cs - (row % 24); if (gc < 0) gc += 24;
      gload_lds16(W + (long)(nt * 64 + row) * 192 + gc * 8, Bl + sI * 8);
    }
    __syncthreads();

    f32x4 acc[2][4];
    #pragma unroll
    for (int r = 0; r < 2; ++r)
      #pragma unroll
      for (int c = 0; c < 4; ++c) acc[r][c] = (f32x4){0.f, 0.f, 0.f, 0.f};

    #pragma unroll
    for (int ks = 0; ks < 6; ++ks) {
      const int l = ks * 4 + quad;
      int pa0 = l + rA0m; if (pa0 >= 24) pa0 -= 24;
      int pa1 = l + rA1m; if (pa1 >= 24) pa1 -= 24;
      bf16x8 a0 = *(const bf16x8*)&Al[rA0 * 192 + pa0 * 8];
      bf16x8 a1 = *(const bf16x8*)&Al[rA1 * 192 + pa1 * 8];
      #pragma unroll
      for (int ct = 0; ct < 4; ++ct) {
        const int rB = ct * 16 + m15;
        int pb = l + (rB % 24); if (pb >= 24) pb -= 24;
        bf16x8 b = *(const bf16x8*)&Bl[rB * 192 + pb * 8];
        acc[0][ct] = __builtin_amdgcn_mfma_f32_16x16x32_bf16(a0, b, acc[0][ct], 0, 0, 0);
        acc[1][ct] = __builtin_amdgcn_mfma_f32_16x16x32_bf16(a1, b, acc[1][ct], 0, 0, 0);
      }
    }
    // epilogue: C/D layout col=lane&15, row=(lane>>4)*4+i  [m89/m91]
    #pragma unroll
    for (int rt = 0; rt < 2; ++rt)
      #pragma unroll
      for (int ct = 0; ct < 4; ++ct)
        #pragma unroll
        for (int i = 0; i < 4; ++i) {
          long row = mBase + wv * 32 + rt * 16 + quad * 4 + i;
          int col = nt * 64 + ct * 16 + m15;
          float v = acc[rt][ct][i] + bias[col];
          if (EPI == 1) {
            v += addin[row * N + col];
            ((float*)outp)[row * N + col] = v;
          } else {
            ((__hip_bfloat16*)outp)[row * N + col] = __float2bfloat16(v);
          }
        }
  }
}

// ===== GEMM variant B: fc2 (K=768, N=192). 4 K-chunks, 3 live n-tile accs ==
__global__ __launch_bounds__(256) void gemmB_kernel(
    const ushort* __restrict__ X, const ushort* __restrict__ W,
    const float* __restrict__ bias, const float* __restrict__ addin,
    float* __restrict__ outp)
{
  __shared__ __align__(16) ushort Al[128 * 192];
  __shared__ __align__(16) ushort Bl[64 * 192];
  const int tid = threadIdx.x;
  const int lane = tid & 63;
  const int wv = tid >> 6;
  const int quad = lane >> 4;
  const int m15 = lane & 15;
  const long mBase = (long)blockIdx.y * 128;

  const int rA0 = wv * 32 + m15, rA1 = rA0 + 16;
  const int rA0m = rA0 % 24, rA1m = rA1 % 24;

  f32x4 acc[3][2][4];
  #pragma unroll
  for (int n = 0; n < 3; ++n)
    #pragma unroll
    for (int r = 0; r < 2; ++r)
      #pragma unroll
      for (int c = 0; c < 4; ++c) acc[n][r][c] = (f32x4){0.f, 0.f, 0.f, 0.f};

  for (int kc = 0; kc < 4; ++kc) {
    for (int nt = 0; nt < 3; ++nt) {
      __syncthreads();
      if (nt == 0) {
        #pragma unroll
        for (int r = 0; r < 12; ++r) {     // stage A chunk
          int sI = tid + r * 256;
          int row = sI / 24;
          int cs = sI - row * 24;
          int gc = cs - (row % 24); if (gc < 0) gc += 24;
          gload_lds16(X + (mBase + row) * 768l + kc * 192 + gc * 8, Al + sI * 8);
        }
      }
      #pragma unroll
      for (int r = 0; r < 6; ++r) {        // stage B tile for (nt, kc)
        int sI = tid + r * 256;
        int row = sI / 24;
        int cs = sI - row * 24;
        int gc = cs - (row % 24); if (gc < 0) gc += 24;
        gload_lds16(W + (long)(nt * 64 + row) * 768 + kc * 192 + gc * 8, Bl + sI * 8);
      }
      __syncthreads();
      #pragma unroll
      for (int ks = 0; ks < 6; ++ks) {
        const int l = ks * 4 + quad;
        int pa0 = l + rA0m; if (pa0 >= 24) pa0 -= 24;
        int pa1 = l + rA1m; if (pa1 >= 24) pa1 -= 24;
        bf16x8 a0 = *(const bf16x8*)&Al[rA0 * 192 + pa0 * 8];
        bf16x8 a1 = *(const bf16x8*)&Al[rA1 * 192 + pa1 * 8];
        #pragma unroll
        for (int ct = 0; ct < 4; ++ct) {
          const int rB = ct * 16 + m15;
          int pb = l + (rB % 24); if (pb >= 24) pb -= 24;
          bf16x8 b = *(const bf16x8*)&Bl[rB * 192 + pb * 8];
          acc[nt][0][ct] = __builtin_amdgcn_mfma_f32_16x16x32_bf16(a0, b, acc[nt][0][ct], 0, 0, 0);
          acc[nt][1][ct] = __builtin_amdgcn_mfma_f32_16x16x32_bf16(a1, b, acc[nt][1][ct], 0, 0, 0);
        }
      }
    }
  }
  #pragma unroll
  for (int nt = 0; nt < 3; ++nt)
    #pragma unroll
    for (int rt = 0; rt < 2; ++rt)
      #pragma unroll
      for (int ct = 0; ct < 4; ++ct)
        #pragma unroll
        for (int i = 0; i < 4; ++i) {
          long row = mBase + wv * 32 + rt * 16 + quad * 4 + i;
          int col = nt * 64 + ct * 16 + m15;
          float v = acc[nt][rt][ct][i] + bias[col] + addin[row * 192 + col];
          outp[row * 192 + col] = v;
        }
}

// -------- window attention: ONE WAVE PER WINDOW-HEAD, barrier-free ----------
__global__ __launch_bounds__(256) void attn_kernel(
    const float* __restrict__ rpe, __hip_bfloat16* __restrict__ qkv)
{
  __shared__ float lds[4 * 2352 + 4 * 172];
  const int tid = threadIdx.x;
  const int lane = tid & 63;
  const int wv = tid >> 6;
  const int wh = blockIdx.x * 4 + wv;
  const int h = wh & 7;
  const int win = wh >> 3;
  const int b = win >> 8;
  const int wl = win & 255;
  const int whi = wl >> 4;
  const int wwi = wl & 15;
  ushort* qkv_u = (ushort*)qkv;
  float* kv_w = &lds[wv * 2352];
  float* bias_w = &lds[4 * 2352 + wv * 172];

  const long rowbase = (long)b * 12544 + (long)(whi * 7) * 112 + wwi * 7;

  #pragma unroll
  for (int rnd = 0; rnd < 10; ++rnd) {
    int e = lane + rnd * 64;
    if (e < 588) {
      int t = e / 12;
      int r = e - t * 12;
      int mat = r / 6;
      int d4 = (r - mat * 6) * 4;
      int py = t / 7, px = t - py * 7;
      long row = rowbase + py * 112 + px;
      ushort4 u = *(const ushort4*)(qkv_u + row * 576 + 192 + mat * 192 + h * 24 + d4);
      float* dst = kv_w + mat * 1176 + t * 24 + d4;
      dst[0] = bfu2f(u.x); dst[1] = bfu2f(u.y);
      dst[2] = bfu2f(u.z); dst[3] = bfu2f(u.w);
    }
  }
  for (int r = lane; r < 169; r += 64) bias_w[r] = rpe[r * 8 + h];
  __syncthreads();

  const int i = (lane < 49) ? lane : 48;
  const int yi = i / 7, xi = i - yi * 7;
  const int base_i = yi * 13 + xi + 84;
  const long myrow = rowbase + yi * 112 + xi;

  float q[24];
  #pragma unroll
  for (int d4 = 0; d4 < 24; d4 += 4) {
    ushort4 u = *(const ushort4*)(qkv_u + myrow * 576 + h * 24 + d4);
    q[d4] = bfu2f(u.x); q[d4 + 1] = bfu2f(u.y);
    q[d4 + 2] = bfu2f(u.z); q[d4 + 3] = bfu2f(u.w);
  }

  float s[49];
  #pragma unroll
  for (int j = 0; j < 49; ++j) {
    const int yj = j / 7, xj = j % 7;
    const int base_j = yj * 13 + xj;
    const float* kr = kv_w + j * 24;
    float acc = 0.f;
    #pragma unroll
    for (int d4 = 0; d4 < 24; d4 += 4) {
      f32x4 kk = *(const f32x4*)(kr + d4);
      acc += q[d4] * kk[0] + q[d4 + 1] * kk[1] + q[d4 + 2] * kk[2] + q[d4 + 3] * kk[3];
    }
    s[j] = acc + bias_w[base_i - base_j];
  }

  float mx = s[0];
  #pragma unroll
  for (int j = 1; j < 49; ++j) mx = fmaxf(mx, s[j]);
  float sm = 0.f;
  #pragma unroll
  for (int j = 0; j < 49; ++j) { s[j] = __expf(s[j] - mx); sm += s[j]; }
  const float inv = 1.f / sm;
  #pragma unroll
  for (int j = 0; j < 49; ++j) s[j] *= inv;

  float o[24];
  #pragma unroll
  for (int d = 0; d < 24; ++d) o[d] = 0.f;
  #pragma unroll
  for (int j = 0; j < 49; ++j) {
    const float p = s[j];
    const float* vr = kv_w + 1176 + j * 24;
    #pragma unroll
    for (int d4 = 0; d4 < 24; d4 += 4) {
      f32x4 vvv = *(const f32x4*)(vr + d4);
      o[d4] += p * vvv[0]; o[d4 + 1] += p * vvv[1];
      o[d4 + 2] += p * vvv[2]; o[d4 + 3] += p * vvv[3];
    }
  }

  if (lane < 49) {
    #pragma unroll
    for (int d4 = 0; d4 < 24; d4 += 4) {
      ushort4 u;
      u.x = f2bfu(o[d4]); u.y = f2bfu(o[d4 + 1]);
      u.z = f2bfu(o[d4 + 2]); u.w = f2bfu(o[d4 + 3]);
      *(ushort4*)(qkv_u + myrow * 576 + h * 24 + d4) = u;
    }
  }
}

// -------- depthwise 3x3 conv + bias + tanh-GELU, w-slide x2 -----------------
// Thread: 4 channels x 2 w-outputs (w0, w0+1), loads 4 columns/row (2x amp
// instead of 3x), rows held packed as ushort4, 4-row macro for load depth.
// grid: (4 h-seg, 56 w-pairs, CB images), 192 threads (= 768 ch / 4).
__global__ __launch_bounds__(192) void dwconv_gelu_kernel(
    const ushort* __restrict__ y1, const float* __restrict__ w,
    const float* __restrict__ bias, ushort* __restrict__ y2)
{
  const int c = threadIdx.x * 4;       // channel group
  const int w0 = blockIdx.y * 2;       // output cols w0, w0+1
  const int b = blockIdx.z;
  const int h0 = blockIdx.x * 28;

  float wt[9][4];
  #pragma unroll
  for (int k = 0; k < 9; ++k)
    #pragma unroll
    for (int j = 0; j < 4; ++j) wt[k][j] = w[(c + j) * 9 + k];
  float bs[4];
  #pragma unroll
  for (int j = 0; j < 4; ++j) bs[j] = bias[c + j];

  const bool okL = (w0 > 0), okR = (w0 + 2 < 112);
  ushort4 rb[6][4];   // rows (ring), cols w0-1..w0+2, packed bf16x4

  auto loadrow = [&](int h, ushort4 dst[4]) {
    const ushort4 z = {0, 0, 0, 0};
    if (h < 0 || h >= 112) {
      dst[0] = z; dst[1] = z; dst[2] = z; dst[3] = z;
      return;
    }
    const ushort* p = y1 + (((size_t)(b * 112 + h)) * 112 + w0) * HID + c;
    dst[0] = okL ? *(const ushort4*)(p - HID) : z;
    dst[1] = *(const ushort4*)(p);
    dst[2] = *(const ushort4*)(p + HID);
    dst[3] = okR ? *(const ushort4*)(p + 2 * HID) : z;
  };

  loadrow(h0 - 1, rb[0]);
  loadrow(h0, rb[1]);

  for (int m = 0; m < 7; ++m) {
    const int hb = h0 + m * 4;
    loadrow(hb + 1, rb[2]);
    loadrow(hb + 2, rb[3]);
    loadrow(hb + 3, rb[4]);
    loadrow(hb + 4, rb[5]);
    #pragma unroll
    for (int o = 0; o < 4; ++o) {
      float acc0[4], acc1[4];
      #pragma unroll
      for (int j = 0; j < 4; ++j) { acc0[j] = bs[j]; acc1[j] = bs[j]; }
      #pragma unroll
      for (int dy = 0; dy < 3; ++dy) {
        float col[4][4];
        #pragma unroll
        for (int x = 0; x < 4; ++x) {
          ushort4 u = rb[o + dy][x];
          col[x][0] = bfu2f(u.x); col[x][1] = bfu2f(u.y);
          col[x][2] = bfu2f(u.z); col[x][3] = bfu2f(u.w);
        }
        #pragma unroll
        for (int dx = 0; dx < 3; ++dx)
          #pragma unroll
          for (int j = 0; j < 4; ++j) {
            acc0[j] += wt[dy * 3 + dx][j] * col[dx][j];
            acc1[j] += wt[dy * 3 + dx][j] * col[dx + 1][j];
          }
      }
      ushort* outp = y2 + (((size_t)(b * 112 + hb + o)) * 112 + w0) * HID + c;
      ushort4 o0, o1;
      o0.x = f2bfu(fgelu(acc0[0])); o0.y = f2bfu(fgelu(acc0[1]));
      o0.z = f2bfu(fgelu(acc0[2])); o0.w = f2bfu(fgelu(acc0[3]));
      o1.x = f2bfu(fgelu(acc1[0])); o1.y = f2bfu(fgelu(acc1[1]));
      o1.z = f2bfu(fgelu(acc1[2])); o1.w = f2bfu(fgelu(acc1[3]));
      *(ushort4*)(outp) = o0;
      *(ushort4*)(outp + HID) = o1;
    }
    #pragma unroll
    for (int x = 0; x < 4; ++x) {
      rb[0][x] = rb[4][x];
      rb[1][x] = rb[5][x];
    }
  }
}

// ---------------------------------------------------------------------------
extern "C" void kernel_launch(void* const* d_in, const int* in_sizes, int n_in,
                              void* d_out, int out_size, void* d_ws, size_t ws_size,
                              hipStream_t stream) {
  const float* x      = (const float*)d_in[0];
  const float* n1g    = (const float*)d_in[1];
  const float* n1b    = (const float*)d_in[2];
  const float* q_w    = (const float*)d_in[3];
  const float* q_b    = (const float*)d_in[4];
  const float* kv_w   = (const float*)d_in[5];
  const float* kv_b   = (const float*)d_in[6];
  const float* rpe    = (const float*)d_in[7];
  const float* proj_w = (const float*)d_in[8];
  const float* proj_b = (const float*)d_in[9];
  const float* n2g    = (const float*)d_in[10];
  const float* n2b    = (const float*)d_in[11];
  const float* fc1_w  = (const float*)d_in[12];
  const float* fc1_b  = (const float*)d_in[13];
  const float* dw_w   = (const float*)d_in[14];
  const float* dw_b   = (const float*)d_in[15];
  const float* fc2_w  = (const float*)d_in[16];
  const float* fc2_b  = (const float*)d_in[17];
  float* out = (float*)d_out;

  // ---- weights at front of ws (~0.9 MB) ----
  char* ws = (char*)d_ws;
  __hip_bfloat16* wcat  = (__hip_bfloat16*)(ws);               // 576*192 bf16
  __hip_bfloat16* projw = (__hip_bfloat16*)(ws + 221184);      // 192*192
  __hip_bfloat16* fc1w  = (__hip_bfloat16*)(ws + 294912);      // 768*192
  __hip_bfloat16* fc2w  = (__hip_bfloat16*)(ws + 589824);      // 192*768
  float* bcat           = (float*)(ws + 884736);               // 576 f32
  const size_t WOFF = 1u << 20;                                // 1 MB

  // ---- pick images-per-chunk CB so the activation buffers fit ws_size ----
  int CB = 8;
  while (CB > 1 && WOFF + (size_t)CB * 12544 * 3456 > ws_size) CB >>= 1;
  const size_t Mc = (size_t)CB * 12544;
  char* Abuf = ws + WOFF;                        // xn / yn   (bf16 Mc x 192)
  char* Bbuf = Abuf + Mc * 384;                  // qkv (Mc x 576) / y2 (Mc x 768)
  char* Cbuf = Bbuf + Mc * 1536;                 // y1 (bf16 Mc x 768)
  __hip_bfloat16* xn  = (__hip_bfloat16*)Abuf;
  __hip_bfloat16* qkv = (__hip_bfloat16*)Bbuf;
  __hip_bfloat16* y2  = (__hip_bfloat16*)Bbuf;
  __hip_bfloat16* y1  = (__hip_bfloat16*)Cbuf;

  prep_kernel<<<576, 256, 0, stream>>>(q_w, q_b, kv_w, kv_b, proj_w, fc1_w,
                                       fc2_w, wcat, bcat, projw, fc1w, fc2w);

  const int nChunks = 8 / CB;
  const int mt = CB * 98;
  for (int cchunk = 0; cchunk < nChunks; ++cchunk) {
    const size_t toff = (size_t)cchunk * Mc;
    const float* xc = x + toff * C_DIM;
    float* oc = out + toff * C_DIM;

    ln_kernel<<<(int)(Mc / 4), 256, 0, stream>>>(xc, n1g, n1b, xn);
    gemmA_kernel<0><<<dim3(1, mt), 256, 0, stream>>>(
        (const ushort*)xn, 192, (const ushort*)wcat, bcat, nullptr, qkv, 576);
    attn_kernel<<<CB * 512, 256, 0, stream>>>(rpe, qkv);
    gemmA_kernel<1><<<dim3(1, mt), 256, 0, stream>>>(
        (const ushort*)qkv, 576, (const ushort*)projw, proj_b, xc, oc, 192);
    ln_kernel<<<(int)(Mc / 4), 256, 0, stream>>>(oc, n2g, n2b, xn);
    gemmA_kernel<0><<<dim3(1, mt), 256, 0, stream>>>(
        (const ushort*)xn, 192, (const ushort*)fc1w, fc1_b, nullptr, y1, 768);
    dwconv_gelu_kernel<<<dim3(4, 56, CB), 192, 0, stream>>>(
        (const ushort*)y1, dw_w, dw_b, (ushort*)y2);
    gemmB_kernel<<<dim3(1, mt), 256, 0, stream>>>(
        (const ushort*)y2, (const ushort*)fc2w, fc2_b, oc, oc);
  }
}